// Round 5
// baseline (1900.709 us; speedup 1.0000x reference)
//
#include <hip/hip_runtime.h>
#include <hip/hip_bf16.h>
#include <math.h>

// TemporalSkeletonBranch — Round 5: MFMA (fp16) rewrite.
// R4 (fp32 VALU, 1852us): MfmaUtil=0, VALUBusy=70%, HBM 0.5% -> compute-bound on the
// wrong pipe. h@W is a GEMM over M=(sample,joint) rows with shared weights -> MFMA.
// Structure: prep kernel converts params (dtype-detected) to fp16 Wt[n][k] + folded BN;
// main kernel: 4 samples/block (M=132 rows, 9 M-tiles), 4 waves x 2 N-tiles,
// h in LDS fp16 XOR-swizzled, GEMM -> Y(LDS) -> VALU epilogue (adjmix/BN/gelu/skip).

#define NJ 33
#define NF 52
#define NH 128
#define NT 256
#define NB 64
#define NSAMP (NB*NT)       // 16384
#define SPB 4               // samples per block
#define MROWS (SPB*NJ)      // 132
#define NBLKS (NSAMP/SPB)   // 4096

typedef unsigned short u16;
typedef _Float16 f16;
typedef f16   half8 __attribute__((ext_vector_type(8)));
typedef float f32x4 __attribute__((ext_vector_type(4)));

// ---- workspace layout ----
// halves region (fp16):
#define HO_W0   0                      // Wt0 [n=128][k=64] (k>=52 zeroed)
#define HO_S0   8192                   // St0 [128][64]
#define HO_W1   16384                  // Wt1 [128][128]
#define HO_W2   32768
#define HO_TW1  49152
#define H_TOTAL 65536                  // halves = 131072 B
// float region (fp32), offsets in floats from ws base:
#define FO_BASE (H_TOTAL/2)            // 32768
#define FO_A0   (FO_BASE+0)            // A0,D0,A1,D1,A2,D2 : 6*128 contiguous
#define FO_SB0  (FO_BASE+768)
#define FO_TB1  (FO_BASE+896)
#define FO_TW2  (FO_BASE+1024)
#define FO_ADJ  (FO_BASE+1152)         // 69 (padded to 80)
#define FO_XT   (FO_BASE+1232)         // [NSAMP][NH] fp32
#define FO_SC   (FO_XT + NSAMP*NH)

__device__ __forceinline__ float bf2f(u16 u) { return __uint_as_float(((unsigned)u) << 16); }
__device__ __forceinline__ float geluf(float v) {
    return 0.5f * v * (1.0f + erff(v * 0.70710678118654752440f));
}
__device__ __forceinline__ float ldv(const void* p, long i, int f) {
    float r;
    if (f) r = bf2f(((const u16*)p)[i]);
    else   r = ((const float*)p)[i];
    return r;
}
// dtype detector (empirically validated in R4: returns 0 for this fp32 dataset).
__device__ int detect_bf16(const void* p) {
    const u16* q = (const u16*)p;
    int nz = 0, ok = 0;
#pragma unroll
    for (int k = 0; k < 64; k++) {
        u16 u = q[k];
        if (u & 0x7FFF) {
            nz++;
            int e = (u >> 7) & 0xFF;
            ok += (e >= 0x40 && e <= 0xBF) ? 1 : 0;
        }
    }
    return (nz == 0) || (ok * 20 >= nz * 19);
}

// adjacency CSR (row-sorted), 69 nnz
#define NNZ 69
constexpr int ADJ_R[NNZ] = {
    0,0,0,0,0, 1, 2,2,2, 3, 4, 5,5,5, 6, 7,7,7, 8,8,8, 9, 10,
    11,11,11,11,11,11,11, 12,12,12,12,12,12,12,
    13,13,13, 14,14,14, 15,15, 16,16,
    17,18,19,20,21,22,
    23,23,23,23, 24,24,24,24,
    25,26,27,28,29,30,31,32 };
constexpr int ADJ_C[NNZ] = {
    0,2,5,11,12, 1, 0,2,7, 3, 4, 0,5,8, 6, 2,7,11, 5,8,12, 9, 10,
    0,7,11,12,13,23,24, 0,8,11,12,14,23,24,
    11,13,15, 12,14,16, 13,15, 14,16,
    17,18,19,20,21,22,
    11,12,23,24, 11,12,23,24,
    25,26,27,28,29,30,31,32 };
constexpr int ROW_PTR[NJ+1] = {
    0,5,6,9,10,11,14,15,18,21,22,23,30,37,40,43,45,47,48,49,50,51,52,53,57,61,
    62,63,64,65,66,67,68,69 };

// ---- prep: dtype detect + fp16 transpose weights + folded BN consts ----
__global__ __launch_bounds__(256) void prep(
    const void* adj,
    const void* W0, const void* b0, const void* S0, const void* sb0,
    const void* g0, const void* be0, const void* m0, const void* v0,
    const void* W1, const void* b1, const void* g1, const void* be1, const void* m1, const void* v1,
    const void* W2, const void* b2, const void* g2, const void* be2, const void* m2, const void* v2,
    const void* tW1, const void* tb1, const void* tW2,
    void* ws)
{
    f16* H = (f16*)ws; float* F = (float*)ws;
    const int bi = blockIdx.x, t = threadIdx.x;
    if (bi == 0) {
        const int fW = detect_bf16(W0), fS = detect_bf16(S0);
        for (int i = t; i < 128*64; i += 256) {
            int n = i >> 6, k = i & 63;
            H[HO_W0 + i] = (f16)(k < NF ? ldv(W0, (long)k*NH + n, fW) : 0.f);
            H[HO_S0 + i] = (f16)(k < NF ? ldv(S0, (long)k*NH + n, fS) : 0.f);
        }
    } else if (bi == 1) {
        const int f = detect_bf16(W1);
        for (int i = t; i < 128*128; i += 256) {
            int n = i >> 7, k = i & 127;
            H[HO_W1 + i] = (f16)ldv(W1, (long)k*NH + n, f);
        }
    } else if (bi == 2) {
        const int f = detect_bf16(W2);
        for (int i = t; i < 128*128; i += 256) {
            int n = i >> 7, k = i & 127;
            H[HO_W2 + i] = (f16)ldv(W2, (long)k*NH + n, f);
        }
    } else if (bi == 3) {
        const int f = detect_bf16(tW1);
        for (int i = t; i < 128*128; i += 256) {
            int n = i >> 7, k = i & 127;
            H[HO_TW1 + i] = (f16)ldv(tW1, (long)k*NH + n, f);
        }
    } else {
        if (t < 128) {
            int c = t;
            {
                float g = ldv(g0,c,detect_bf16(g0)), be = ldv(be0,c,detect_bf16(be0));
                float m = ldv(m0,c,detect_bf16(m0)), v = ldv(v0,c,detect_bf16(v0));
                float b = ldv(b0,c,detect_bf16(b0));
                float A = g * rsqrtf(v + 1e-5f);
                F[FO_A0 + 0*256 + c] = A; F[FO_A0 + 0*256 + 128 + c] = (b - m)*A + be;
            }
            {
                float g = ldv(g1,c,detect_bf16(g1)), be = ldv(be1,c,detect_bf16(be1));
                float m = ldv(m1,c,detect_bf16(m1)), v = ldv(v1,c,detect_bf16(v1));
                float b = ldv(b1,c,detect_bf16(b1));
                float A = g * rsqrtf(v + 1e-5f);
                F[FO_A0 + 1*256 + c] = A; F[FO_A0 + 1*256 + 128 + c] = (b - m)*A + be;
            }
            {
                float g = ldv(g2,c,detect_bf16(g2)), be = ldv(be2,c,detect_bf16(be2));
                float m = ldv(m2,c,detect_bf16(m2)), v = ldv(v2,c,detect_bf16(v2));
                float b = ldv(b2,c,detect_bf16(b2));
                float A = g * rsqrtf(v + 1e-5f);
                F[FO_A0 + 2*256 + c] = A; F[FO_A0 + 2*256 + 128 + c] = (b - m)*A + be;
            }
            F[FO_SB0 + c] = ldv(sb0, c, detect_bf16(sb0));
            F[FO_TB1 + c] = ldv(tb1, c, detect_bf16(tb1));
            F[FO_TW2 + c] = ldv(tW2, c, detect_bf16(tW2));
        }
        if (t < NNZ) {
            int fA = detect_bf16(adj);
            F[FO_ADJ + t] = ldv(adj, (long)ADJ_R[t]*NJ + ADJ_C[t], fA);
        }
    }
}

// ---- main: fused 3-layer GCN via MFMA + mean + score ----
__global__ __launch_bounds__(256, 2) void gcn_mfma(const void* __restrict__ x,
                                                   void* __restrict__ ws)
{
    const f16* HW = (const f16*)ws;
    float* F = (float*)ws;
    float* xt_g = F + FO_XT;
    float* sc_g = F + FO_SC;

    __shared__ f16 smem[2 * MROWS * NH];          // hb [132][128] + Yb [132][128], 67.6 KB
    f16* hb = smem;
    f16* Yb = smem + MROWS * NH;
    __shared__ float sADf[768];                   // A0,D0,A1,D1,A2,D2
    __shared__ float sSB0[128], sTB1[128], sTW2[128];
    __shared__ float sADJ[NNZ];
    __shared__ float xtb[512];
    __shared__ float rbuf[256];
    __shared__ int sfx;

    const int t    = threadIdx.x;
    const int lane = t & 63;
    const int wv   = t >> 6;
    const int q    = lane >> 4;
    const int ml   = lane & 15;
    const int n0   = wv * 32;

    if (t == 0) sfx = detect_bf16(x);
    for (int i = t; i < 768; i += 256) sADf[i] = F[FO_A0 + i];
    if (t < 128) { sSB0[t] = F[FO_SB0+t]; sTB1[t] = F[FO_TB1+t]; sTW2[t] = F[FO_TW2+t]; }
    if (t < NNZ) sADJ[t] = F[FO_ADJ + t];
    __syncthreads();

    // ---- stage x -> hb, fp16, K=64 layout (blk^(r&7) swizzle), pad cols 52..63 = 0 ----
    {
        const int fX = sfx;
        const long xbase = (long)blockIdx.x * (SPB * NJ * NF);
        for (int it = 0; it < 5; it++) {
            int g = t + it * 256;
            if (g < MROWS * 8) {
                int r = g >> 3, blk = g & 7;
                long rb = xbase + (long)r * NF;
                half8 o;
#pragma unroll
                for (int i = 0; i < 8; i++) {
                    int c = blk * 8 + i;
                    o[i] = (f16)(c < NF ? ldv(x, rb + c, fX) : 0.f);
                }
                *(half8*)(hb + r * 128 + ((blk ^ (r & 7)) << 3)) = o;
            }
        }
    }

    f32x4 acc[9][2];
    const f32x4 z4 = {0.f, 0.f, 0.f, 0.f};

    auto gemm64 = [&](const half8 bf[2][2]) {
#pragma unroll
        for (int mt = 0; mt < 9; mt++) {
            const int m = mt * 16 + ml;
            half8 af[2];
#pragma unroll
            for (int ks = 0; ks < 2; ks++)
                af[ks] = *(const half8*)(hb + m * 128 + ((((ks << 2) + q) ^ (ml & 7)) << 3));
#pragma unroll
            for (int nt = 0; nt < 2; nt++)
#pragma unroll
                for (int ks = 0; ks < 2; ks++)
                    acc[mt][nt] = __builtin_amdgcn_mfma_f32_16x16x32_f16(af[ks], bf[nt][ks], acc[mt][nt], 0, 0, 0);
        }
    };

    auto writeY = [&]() {
#pragma unroll
        for (int mt = 0; mt < 9; mt++)
#pragma unroll
            for (int nt = 0; nt < 2; nt++)
#pragma unroll
                for (int r4 = 0; r4 < 4; r4++) {
                    int rr = mt * 16 + q * 4 + r4;
                    if (rr < MROWS) Yb[rr * 128 + n0 + nt * 16 + ml] = (f16)acc[mt][nt][r4];
                }
    };

    auto writeSkip = [&]() {   // C-frags -> hb in swizzled h-layout
#pragma unroll
        for (int mt = 0; mt < 9; mt++)
#pragma unroll
            for (int nt = 0; nt < 2; nt++)
#pragma unroll
                for (int r4 = 0; r4 < 4; r4++) {
                    int rr = mt * 16 + q * 4 + r4;
                    int cc = n0 + nt * 16 + ml;
                    if (rr < MROWS)
                        hb[rr * 128 + (((cc >> 3) ^ (rr & 15)) << 3) + (cc & 7)] = (f16)acc[mt][nt][r4];
                }
    };

    auto epilogue = [&](int L, bool l0) {
#pragma unroll 1
        for (int it = 0; it < 9; it++) {
            int g = t + it * 256;
            if (g >= MROWS * 16) break;
            int r = g >> 4, blk = g & 15;
            int s = (r * 993) >> 15;     // r/33 for r<132
            int j = r - 33 * s;
            float z[8];
#pragma unroll
            for (int i = 0; i < 8; i++) z[i] = 0.f;
            for (int e = ROW_PTR[j]; e < ROW_PTR[j + 1]; e++) {
                float w = sADJ[e];
                const half8 yv = *(const half8*)(Yb + (s * NJ + ADJ_C[e]) * 128 + blk * 8);
#pragma unroll
                for (int i = 0; i < 8; i++) z[i] = fmaf(w, (float)yv[i], z[i]);
            }
            int c0 = blk * 8;
            f16* hp = hb + r * 128 + ((blk ^ (r & 15)) << 3);
            half8 hv = *(const half8*)hp;   // skip / h_prev (swizzled h-layout)
            half8 o;
#pragma unroll
            for (int i = 0; i < 8; i++) {
                float zb = fmaf(z[i], sADf[L * 256 + c0 + i], sADf[L * 256 + 128 + c0 + i]);
                float h = geluf(zb) + (float)hv[i] + (l0 ? sSB0[c0 + i] : 0.f);
                o[i] = (f16)h;
            }
            *(half8*)hp = o;
        }
    };

    // ---------------- layer 0 (K=64): Y = x@W0 ; skip = x@S0 ----------------
    {
        half8 bw[2][2], bs[2][2];
#pragma unroll
        for (int nt = 0; nt < 2; nt++)
#pragma unroll
            for (int ks = 0; ks < 2; ks++) {
                int n = n0 + nt * 16 + ml;
                bw[nt][ks] = *(const half8*)(HW + HO_W0 + n * 64 + ks * 32 + q * 8);
                bs[nt][ks] = *(const half8*)(HW + HO_S0 + n * 64 + ks * 32 + q * 8);
            }
        __syncthreads();                       // x fully staged
#pragma unroll
        for (int mt = 0; mt < 9; mt++) { acc[mt][0] = z4; acc[mt][1] = z4; }
        gemm64(bw);
        writeY();                              // Yb writes; other waves' stray A-reads of rows>=132 are don't-care
#pragma unroll
        for (int mt = 0; mt < 9; mt++) { acc[mt][0] = z4; acc[mt][1] = z4; }
        gemm64(bs);                            // still reads x from hb (untouched)
        __syncthreads();                       // all x reads + Y writes complete
        writeSkip();                           // hb <- skip (clobbers x, now dead)
        __syncthreads();
        epilogue(0, true);                     // hb <- gelu(bn0(adj@Y)) + skip + sb0
        __syncthreads();
    }

    // ---------------- layers 1,2 (K=128) ----------------
    auto dolayer = [&](const f16* Wt, int L) {
        half8 bf[2][4];
#pragma unroll
        for (int nt = 0; nt < 2; nt++)
#pragma unroll
            for (int ks = 0; ks < 4; ks++)
                bf[nt][ks] = *(const half8*)(Wt + (n0 + nt * 16 + ml) * 128 + ks * 32 + q * 8);
#pragma unroll
        for (int mt = 0; mt < 9; mt++) { acc[mt][0] = z4; acc[mt][1] = z4; }
#pragma unroll
        for (int mt = 0; mt < 9; mt++) {
            const int m = mt * 16 + ml;
            half8 af[4];
#pragma unroll
            for (int ks = 0; ks < 4; ks++)
                af[ks] = *(const half8*)(hb + m * 128 + ((((ks << 2) + q) ^ ml) << 3));
#pragma unroll
            for (int nt = 0; nt < 2; nt++)
#pragma unroll
                for (int ks = 0; ks < 4; ks++)
                    acc[mt][nt] = __builtin_amdgcn_mfma_f32_16x16x32_f16(af[ks], bf[nt][ks], acc[mt][nt], 0, 0, 0);
        }
        writeY();
        __syncthreads();                       // Y complete + all hb reads done
        epilogue(L, false);                    // hb <- gelu(bnL(adj@Y)) + h  (in-place per element)
        __syncthreads();
    };
    dolayer(HW + HO_W1, 1);
    dolayer(HW + HO_W2, 2);

    // ---------------- mean over joints + attention score MLP ----------------
#pragma unroll
    for (int p = 0; p < 2; p++) {
        int id = t + 256 * p, s = id >> 7, c = id & 127;
        int blk = c >> 3, off = c & 7;
        float sum = 0.f;
#pragma unroll
        for (int j = 0; j < NJ; j++) {
            int r = s * NJ + j;
            sum += (float)hb[r * 128 + ((blk ^ (r & 15)) << 3) + off];
        }
        float xtc = sum * (1.0f / 33.0f);
        xt_g[((long)blockIdx.x * SPB + s) * NH + c] = xtc;
        xtb[id] = xtc;
    }
    __syncthreads();

    for (int p = 0; p < 2; p++) {
        int id = t + 256 * p, s = id >> 7, c = id & 127;
        float u = 0.f;
#pragma unroll
        for (int kk = 0; kk < 16; kk++) {
            half8 wvv = *(const half8*)(HW + HO_TW1 + c * 128 + kk * 8);
#pragma unroll
            for (int i = 0; i < 8; i++) u = fmaf(xtb[s * 128 + kk * 8 + i], (float)wvv[i], u);
        }
        rbuf[t] = geluf(u + sTB1[c]) * sTW2[c];   // tb2 omitted: softmax shift-invariant
        __syncthreads();
#pragma unroll
        for (int st = 64; st > 0; st >>= 1) {
            if ((t & 127) < st) rbuf[t] += rbuf[t + st];
            __syncthreads();
        }
        if ((t & 127) == 0) sc_g[blockIdx.x * SPB + (t >> 7) + 2 * p] = rbuf[t];
        __syncthreads();
    }
}

// ---- softmax over T + weighted sum -> out[B,H] (dtype-matched, from R4) ----
__global__ __launch_bounds__(256) void attn_pool(
    const void* __restrict__ x,
    const float* __restrict__ xt_ws, const float* __restrict__ score_ws,
    void* __restrict__ out)
{
    __shared__ float sc[NT];
    __shared__ float ew[NT];
    __shared__ float pb[256];
    __shared__ int sfx2;
    const int tid = threadIdx.x, b = blockIdx.x;

    if (tid == 0) sfx2 = detect_bf16(x);
    sc[tid] = score_ws[b * NT + tid];
    __syncthreads();
    float mx = -1e30f;
#pragma unroll 8
    for (int i = 0; i < NT; i++) mx = fmaxf(mx, sc[i]);
    ew[tid] = expf(sc[tid] - mx);
    __syncthreads();
    float den = 0.f;
#pragma unroll 8
    for (int i = 0; i < NT; i++) den += ew[i];

    const int c = tid & 127, th = tid >> 7;
    float acc = 0.f;
    const float* xp = xt_ws + ((size_t)b * NT + th * 128) * NH + c;
#pragma unroll 4
    for (int i = 0; i < 128; i++) acc = fmaf(ew[th * 128 + i], xp[(size_t)i * NH], acc);
    pb[tid] = acc;
    __syncthreads();
    if (tid < NH) {
        float r = (pb[tid] + pb[tid + 128]) / den;
        if (sfx2) ((__hip_bfloat16*)out)[b * NH + tid] = __float2bfloat16(r);
        else      ((float*)out)[b * NH + tid] = r;
    }
}

extern "C" void kernel_launch(void* const* d_in, const int* in_sizes, int n_in,
                              void* d_out, int out_size, void* d_ws, size_t ws_size,
                              hipStream_t stream) {
    prep<<<5, 256, 0, stream>>>(
        d_in[1],                                   // adj
        d_in[2], d_in[3], d_in[4], d_in[5],        // W0 b0 S0 sb0
        d_in[6], d_in[7], d_in[8], d_in[9],        // g0 be0 m0 v0
        d_in[10], d_in[11], d_in[12], d_in[13], d_in[14], d_in[15],  // W1 b1 g1 be1 m1 v1
        d_in[16], d_in[17], d_in[18], d_in[19], d_in[20], d_in[21],  // W2 b2 g2 be2 m2 v2
        d_in[22], d_in[23], d_in[24],              // tW1 tb1 tW2
        d_ws);
    gcn_mfma<<<NBLKS, 256, 0, stream>>>(d_in[0], d_ws);
    float* F = (float*)d_ws;
    attn_pool<<<NB, 256, 0, stream>>>(d_in[0], F + FO_XT, F + FO_SC, d_out);
}

// Round 6
// 877.213 us; speedup vs baseline: 2.1668x; 2.1668x over previous
//
#include <hip/hip_runtime.h>
#include <hip/hip_bf16.h>
#include <math.h>

// TemporalSkeletonBranch — Round 6: MFMA, spill-proof restructure.
// R5 diagnosis: WRITE_SIZE 1.38 GB/dispatch of compiler scratch (lambdas with
// array params + 72-f32 acc live across 4 phases) -> L2 thrash -> weight refetch
// (FETCH 592 MB) -> HBM-traffic-bound at 1.7 ms. R6: same validated layouts,
// straight-line code, SPB=2 (acc[5][2]), no launch-bounds cap, Yb stride 136.

#define NJ 33
#define NF 52
#define NH 128
#define NT 256
#define NB 64
#define NSAMP (NB*NT)       // 16384
#define SPB 2               // samples per block
#define MROWS (SPB*NJ)      // 66
#define RPAD 80             // padded rows (5 M-tiles)
#define MTI 5               // M-tiles
#define NBLKS (NSAMP/SPB)   // 8192
#define YSTR 136            // Yb row stride in halves (bank-depadded)

typedef unsigned short u16;
typedef _Float16 f16;
typedef f16   half8 __attribute__((ext_vector_type(8)));
typedef float f32x4 __attribute__((ext_vector_type(4)));

// ---- workspace layout (identical to R5, proven) ----
#define HO_W0   0
#define HO_S0   8192
#define HO_W1   16384
#define HO_W2   32768
#define HO_TW1  49152
#define H_TOTAL 65536
#define FO_BASE (H_TOTAL/2)
#define FO_A0   (FO_BASE+0)            // A0,D0,A1,D1,A2,D2 blocks of 128
#define FO_SB0  (FO_BASE+768)
#define FO_TB1  (FO_BASE+896)
#define FO_TW2  (FO_BASE+1024)
#define FO_ADJ  (FO_BASE+1152)
#define FO_XT   (FO_BASE+1232)
#define FO_SC   (FO_XT + NSAMP*NH)

__device__ __forceinline__ float bf2f(u16 u) { return __uint_as_float(((unsigned)u) << 16); }
__device__ __forceinline__ float geluf(float v) {
    return 0.5f * v * (1.0f + erff(v * 0.70710678118654752440f));
}
__device__ __forceinline__ float ldv(const void* p, long i, int f) {
    float r;
    if (f) r = bf2f(((const u16*)p)[i]);
    else   r = ((const float*)p)[i];
    return r;
}
__device__ int detect_bf16(const void* p) {
    const u16* q = (const u16*)p;
    int nz = 0, ok = 0;
#pragma unroll
    for (int k = 0; k < 64; k++) {
        u16 u = q[k];
        if (u & 0x7FFF) {
            nz++;
            int e = (u >> 7) & 0xFF;
            ok += (e >= 0x40 && e <= 0xBF) ? 1 : 0;
        }
    }
    return (nz == 0) || (ok * 20 >= nz * 19);
}

#define NNZ 69
constexpr int ADJ_R[NNZ] = {
    0,0,0,0,0, 1, 2,2,2, 3, 4, 5,5,5, 6, 7,7,7, 8,8,8, 9, 10,
    11,11,11,11,11,11,11, 12,12,12,12,12,12,12,
    13,13,13, 14,14,14, 15,15, 16,16,
    17,18,19,20,21,22,
    23,23,23,23, 24,24,24,24,
    25,26,27,28,29,30,31,32 };
constexpr int ADJ_C[NNZ] = {
    0,2,5,11,12, 1, 0,2,7, 3, 4, 0,5,8, 6, 2,7,11, 5,8,12, 9, 10,
    0,7,11,12,13,23,24, 0,8,11,12,14,23,24,
    11,13,15, 12,14,16, 13,15, 14,16,
    17,18,19,20,21,22,
    11,12,23,24, 11,12,23,24,
    25,26,27,28,29,30,31,32 };
constexpr int ROW_PTR[NJ+1] = {
    0,5,6,9,10,11,14,15,18,21,22,23,30,37,40,43,45,47,48,49,50,51,52,53,57,61,
    62,63,64,65,66,67,68,69 };

// ---- prep: dtype detect + fp16 transposed weights + folded BN (R5-proven) ----
__global__ __launch_bounds__(256) void prep(
    const void* adj,
    const void* W0, const void* b0, const void* S0, const void* sb0,
    const void* g0, const void* be0, const void* m0, const void* v0,
    const void* W1, const void* b1, const void* g1, const void* be1, const void* m1, const void* v1,
    const void* W2, const void* b2, const void* g2, const void* be2, const void* m2, const void* v2,
    const void* tW1, const void* tb1, const void* tW2,
    void* ws)
{
    f16* H = (f16*)ws; float* F = (float*)ws;
    const int bi = blockIdx.x, t = threadIdx.x;
    if (bi == 0) {
        const int fW = detect_bf16(W0), fS = detect_bf16(S0);
        for (int i = t; i < 128*64; i += 256) {
            int n = i >> 6, k = i & 63;
            H[HO_W0 + i] = (f16)(k < NF ? ldv(W0, (long)k*NH + n, fW) : 0.f);
            H[HO_S0 + i] = (f16)(k < NF ? ldv(S0, (long)k*NH + n, fS) : 0.f);
        }
    } else if (bi == 1) {
        const int f = detect_bf16(W1);
        for (int i = t; i < 128*128; i += 256) {
            int n = i >> 7, k = i & 127;
            H[HO_W1 + i] = (f16)ldv(W1, (long)k*NH + n, f);
        }
    } else if (bi == 2) {
        const int f = detect_bf16(W2);
        for (int i = t; i < 128*128; i += 256) {
            int n = i >> 7, k = i & 127;
            H[HO_W2 + i] = (f16)ldv(W2, (long)k*NH + n, f);
        }
    } else if (bi == 3) {
        const int f = detect_bf16(tW1);
        for (int i = t; i < 128*128; i += 256) {
            int n = i >> 7, k = i & 127;
            H[HO_TW1 + i] = (f16)ldv(tW1, (long)k*NH + n, f);
        }
    } else {
        if (t < 128) {
            int c = t;
            {
                float g = ldv(g0,c,detect_bf16(g0)), be = ldv(be0,c,detect_bf16(be0));
                float m = ldv(m0,c,detect_bf16(m0)), v = ldv(v0,c,detect_bf16(v0));
                float b = ldv(b0,c,detect_bf16(b0));
                float A = g * rsqrtf(v + 1e-5f);
                F[FO_A0 + 0*256 + c] = A; F[FO_A0 + 0*256 + 128 + c] = (b - m)*A + be;
            }
            {
                float g = ldv(g1,c,detect_bf16(g1)), be = ldv(be1,c,detect_bf16(be1));
                float m = ldv(m1,c,detect_bf16(m1)), v = ldv(v1,c,detect_bf16(v1));
                float b = ldv(b1,c,detect_bf16(b1));
                float A = g * rsqrtf(v + 1e-5f);
                F[FO_A0 + 1*256 + c] = A; F[FO_A0 + 1*256 + 128 + c] = (b - m)*A + be;
            }
            {
                float g = ldv(g2,c,detect_bf16(g2)), be = ldv(be2,c,detect_bf16(be2));
                float m = ldv(m2,c,detect_bf16(m2)), v = ldv(v2,c,detect_bf16(v2));
                float b = ldv(b2,c,detect_bf16(b2));
                float A = g * rsqrtf(v + 1e-5f);
                F[FO_A0 + 2*256 + c] = A; F[FO_A0 + 2*256 + 128 + c] = (b - m)*A + be;
            }
            F[FO_SB0 + c] = ldv(sb0, c, detect_bf16(sb0));
            F[FO_TB1 + c] = ldv(tb1, c, detect_bf16(tb1));
            F[FO_TW2 + c] = ldv(tW2, c, detect_bf16(tW2));
        }
        if (t < NNZ) {
            int fA = detect_bf16(adj);
            F[FO_ADJ + t] = ldv(adj, (long)ADJ_R[t]*NJ + ADJ_C[t], fA);
        }
    }
}

// ==== epilogue macro: z = adj@Y (from Yb), h' = gelu(z*A+D) + h [+ sb0], RMW hb ====
#define EPILOGUE(Lidx, ISL0)                                                        \
    _Pragma("unroll 1")                                                             \
    for (int it = 0; it < 5; it++) {                                                \
        int g = t + it * 256;                                                       \
        if (g < MROWS * 16) {                                                       \
            int r = g >> 4, blk = g & 15;                                           \
            int s = (r >= NJ) ? 1 : 0;                                              \
            int j = r - NJ * s;                                                     \
            float z[8];                                                             \
            _Pragma("unroll")                                                       \
            for (int i = 0; i < 8; i++) z[i] = 0.f;                                 \
            int e0 = sRP[j], e1 = sRP[j + 1];                                       \
            for (int e = e0; e < e1; e++) {                                         \
                float w = sADJ[e];                                                  \
                const half8 yv = *(const half8*)(Yb + (s * NJ + sCOL[e]) * YSTR + blk * 8); \
                _Pragma("unroll")                                                   \
                for (int i = 0; i < 8; i++) z[i] = fmaf(w, (float)yv[i], z[i]);     \
            }                                                                       \
            int c0 = blk * 8;                                                       \
            f16* hp = hb + r * 128 + ((blk ^ (r & 15)) << 3);                       \
            half8 hv = *(const half8*)hp;                                           \
            half8 o;                                                                \
            _Pragma("unroll")                                                       \
            for (int i = 0; i < 8; i++) {                                           \
                float zb = fmaf(z[i], sADf[(Lidx) * 256 + c0 + i], sADf[(Lidx) * 256 + 128 + c0 + i]); \
                float h = geluf(zb) + (float)hv[i] + ((ISL0) ? sSB0[c0 + i] : 0.f); \
                o[i] = (f16)h;                                                      \
            }                                                                       \
            *(half8*)hp = o;                                                        \
        }                                                                           \
    }

// ==== write acc C-frags into Yb (padded stride) ====
#define WRITE_Y(ACC)                                                                \
    _Pragma("unroll")                                                               \
    for (int mt = 0; mt < MTI; mt++)                                                \
        _Pragma("unroll")                                                           \
        for (int nt = 0; nt < 2; nt++)                                              \
            _Pragma("unroll")                                                       \
            for (int r4 = 0; r4 < 4; r4++) {                                        \
                int rr = mt * 16 + q * 4 + r4;                                      \
                if (rr < MROWS) Yb[rr * YSTR + n0 + nt * 16 + ml] = (f16)ACC[mt][nt][r4]; \
            }

// ---- main: fused 3-layer GCN via MFMA + mean + score ----
__global__ __launch_bounds__(256) void gcn_mfma(const void* __restrict__ x,
                                                void* __restrict__ ws)
{
    const f16* HW = (const f16*)ws;
    float* F = (float*)ws;
    float* xt_g = F + FO_XT;
    float* sc_g = F + FO_SC;

    __shared__ f16 hb[RPAD * 128];        // 20.5 KB
    __shared__ f16 Yb[RPAD * YSTR];       // 21.8 KB
    __shared__ float sADf[768];
    __shared__ float sSB0[128], sTB1[128], sTW2[128];
    __shared__ float sADJ[NNZ];
    __shared__ int   sCOL[NNZ];
    __shared__ int   sRP[NJ + 1];
    __shared__ float xtb[256];
    __shared__ float rbuf[256];
    __shared__ int sfx;

    const int t    = threadIdx.x;
    const int lane = t & 63;
    const int wv   = t >> 6;
    const int q    = lane >> 4;
    const int ml   = lane & 15;
    const int n0   = wv * 32;

    if (t == 0) sfx = detect_bf16(x);
    for (int i = t; i < 768; i += 256) sADf[i] = F[FO_A0 + i];
    if (t < 128) { sSB0[t] = F[FO_SB0+t]; sTB1[t] = F[FO_TB1+t]; sTW2[t] = F[FO_TW2+t]; }
    if (t < NNZ) { sADJ[t] = F[FO_ADJ + t]; sCOL[t] = ADJ_C[t]; }
    if (t < NJ + 1) sRP[t] = ROW_PTR[t];
    __syncthreads();

    // ---- stage x -> hb rows [0,66), K=64 layout, chunk swizzle blk^(r&7) ----
    {
        const int fX = sfx;
        const long xbase = (long)blockIdx.x * (SPB * NJ * NF);
#pragma unroll 1
        for (int it = 0; it < 3; it++) {
            int g = t + it * 256;
            if (g < MROWS * 8) {
                int r = g >> 3, blk = g & 7;
                long rb = xbase + (long)r * NF;
                half8 o;
#pragma unroll
                for (int i = 0; i < 8; i++) {
                    int c = blk * 8 + i;
                    o[i] = (f16)(c < NF ? ldv(x, rb + c, fX) : 0.f);
                }
                *(half8*)(hb + r * 128 + ((blk ^ (r & 7)) << 3)) = o;
            }
        }
    }

    f32x4 acc[MTI][2];
    const f32x4 z4 = {0.f, 0.f, 0.f, 0.f};

    // ================= layer 0 (K=64): Y = x@W0, skip = x@S0, one A sweep =================
    {
        half8 bw[2][2], bs[2][2];
#pragma unroll
        for (int nt = 0; nt < 2; nt++)
#pragma unroll
            for (int ks = 0; ks < 2; ks++) {
                int n = n0 + nt * 16 + ml;
                bw[nt][ks] = *(const half8*)(HW + HO_W0 + n * 64 + ks * 32 + q * 8);
                bs[nt][ks] = *(const half8*)(HW + HO_S0 + n * 64 + ks * 32 + q * 8);
            }
        f32x4 acs[MTI][2];
#pragma unroll
        for (int mt = 0; mt < MTI; mt++) { acc[mt][0] = z4; acc[mt][1] = z4; acs[mt][0] = z4; acs[mt][1] = z4; }
        __syncthreads();                   // x staged
#pragma unroll
        for (int mt = 0; mt < MTI; mt++) {
            const int m = mt * 16 + ml;
            half8 a0 = *(const half8*)(hb + m * 128 + ((q ^ (ml & 7)) << 3));
            half8 a1 = *(const half8*)(hb + m * 128 + (((4 + q) ^ (ml & 7)) << 3));
            acc[mt][0] = __builtin_amdgcn_mfma_f32_16x16x32_f16(a0, bw[0][0], acc[mt][0], 0, 0, 0);
            acc[mt][0] = __builtin_amdgcn_mfma_f32_16x16x32_f16(a1, bw[0][1], acc[mt][0], 0, 0, 0);
            acc[mt][1] = __builtin_amdgcn_mfma_f32_16x16x32_f16(a0, bw[1][0], acc[mt][1], 0, 0, 0);
            acc[mt][1] = __builtin_amdgcn_mfma_f32_16x16x32_f16(a1, bw[1][1], acc[mt][1], 0, 0, 0);
            acs[mt][0] = __builtin_amdgcn_mfma_f32_16x16x32_f16(a0, bs[0][0], acs[mt][0], 0, 0, 0);
            acs[mt][0] = __builtin_amdgcn_mfma_f32_16x16x32_f16(a1, bs[0][1], acs[mt][0], 0, 0, 0);
            acs[mt][1] = __builtin_amdgcn_mfma_f32_16x16x32_f16(a0, bs[1][0], acs[mt][1], 0, 0, 0);
            acs[mt][1] = __builtin_amdgcn_mfma_f32_16x16x32_f16(a1, bs[1][1], acs[mt][1], 0, 0, 0);
        }
        WRITE_Y(acc)
        __syncthreads();                   // Yb complete + all x A-reads done
        // skip -> hb (clobbers x) in 16-chunk h swizzle
#pragma unroll
        for (int mt = 0; mt < MTI; mt++)
#pragma unroll
            for (int nt = 0; nt < 2; nt++)
#pragma unroll
                for (int r4 = 0; r4 < 4; r4++) {
                    int rr = mt * 16 + q * 4 + r4;
                    int cc = n0 + nt * 16 + ml;
                    if (rr < MROWS)
                        hb[rr * 128 + (((cc >> 3) ^ (rr & 15)) << 3) + (cc & 7)] = (f16)acs[mt][nt][r4];
                }
        __syncthreads();
        EPILOGUE(0, 1)
        __syncthreads();
    }

    // ================= layer 1 (K=128) =================
    {
        half8 bf[2][4];
#pragma unroll
        for (int nt = 0; nt < 2; nt++)
#pragma unroll
            for (int ks = 0; ks < 4; ks++)
                bf[nt][ks] = *(const half8*)(HW + HO_W1 + (n0 + nt * 16 + ml) * 128 + ks * 32 + q * 8);
#pragma unroll
        for (int mt = 0; mt < MTI; mt++) { acc[mt][0] = z4; acc[mt][1] = z4; }
#pragma unroll
        for (int mt = 0; mt < MTI; mt++) {
            const int m = mt * 16 + ml;
#pragma unroll
            for (int ks = 0; ks < 4; ks++) {
                half8 af = *(const half8*)(hb + m * 128 + ((((ks << 2) + q) ^ ml) << 3));
                acc[mt][0] = __builtin_amdgcn_mfma_f32_16x16x32_f16(af, bf[0][ks], acc[mt][0], 0, 0, 0);
                acc[mt][1] = __builtin_amdgcn_mfma_f32_16x16x32_f16(af, bf[1][ks], acc[mt][1], 0, 0, 0);
            }
        }
        WRITE_Y(acc)
        __syncthreads();
        EPILOGUE(1, 0)
        __syncthreads();
    }

    // ================= layer 2 (K=128) =================
    {
        half8 bf[2][4];
#pragma unroll
        for (int nt = 0; nt < 2; nt++)
#pragma unroll
            for (int ks = 0; ks < 4; ks++)
                bf[nt][ks] = *(const half8*)(HW + HO_W2 + (n0 + nt * 16 + ml) * 128 + ks * 32 + q * 8);
#pragma unroll
        for (int mt = 0; mt < MTI; mt++) { acc[mt][0] = z4; acc[mt][1] = z4; }
#pragma unroll
        for (int mt = 0; mt < MTI; mt++) {
            const int m = mt * 16 + ml;
#pragma unroll
            for (int ks = 0; ks < 4; ks++) {
                half8 af = *(const half8*)(hb + m * 128 + ((((ks << 2) + q) ^ ml) << 3));
                acc[mt][0] = __builtin_amdgcn_mfma_f32_16x16x32_f16(af, bf[0][ks], acc[mt][0], 0, 0, 0);
                acc[mt][1] = __builtin_amdgcn_mfma_f32_16x16x32_f16(af, bf[1][ks], acc[mt][1], 0, 0, 0);
            }
        }
        WRITE_Y(acc)
        __syncthreads();
        EPILOGUE(2, 0)
        __syncthreads();
    }

    // ================= mean over joints + attention score MLP =================
    {
        const int s = t >> 7, c = t & 127;
        const int blk = c >> 3, off = c & 7;
        float sum = 0.f;
#pragma unroll
        for (int j = 0; j < NJ; j++) {
            int r = s * NJ + j;
            sum += (float)hb[r * 128 + ((blk ^ (r & 15)) << 3) + off];
        }
        float xtc = sum * (1.0f / 33.0f);
        xt_g[((long)blockIdx.x * SPB + s) * NH + c] = xtc;
        xtb[t] = xtc;
        __syncthreads();

        float u = 0.f;
#pragma unroll
        for (int kk = 0; kk < 16; kk++) {
            half8 wvv = *(const half8*)(HW + HO_TW1 + c * 128 + kk * 8);
#pragma unroll
            for (int i = 0; i < 8; i++) u = fmaf(xtb[s * 128 + kk * 8 + i], (float)wvv[i], u);
        }
        rbuf[t] = geluf(u + sTB1[c]) * sTW2[c];   // tb2 omitted: softmax shift-invariant
        __syncthreads();
#pragma unroll
        for (int st = 64; st > 0; st >>= 1) {
            if ((t & 127) < st) rbuf[t] += rbuf[t + st];
            __syncthreads();
        }
        if ((t & 127) == 0) sc_g[blockIdx.x * SPB + s] = rbuf[t];
    }
}

// ---- softmax over T + weighted sum -> out[B,H] (dtype-matched, R4-proven) ----
__global__ __launch_bounds__(256) void attn_pool(
    const void* __restrict__ x,
    const float* __restrict__ xt_ws, const float* __restrict__ score_ws,
    void* __restrict__ out)
{
    __shared__ float sc[NT];
    __shared__ float ew[NT];
    __shared__ float pb[256];
    __shared__ int sfx2;
    const int tid = threadIdx.x, b = blockIdx.x;

    if (tid == 0) sfx2 = detect_bf16(x);
    sc[tid] = score_ws[b * NT + tid];
    __syncthreads();
    float mx = -1e30f;
#pragma unroll 8
    for (int i = 0; i < NT; i++) mx = fmaxf(mx, sc[i]);
    ew[tid] = expf(sc[tid] - mx);
    __syncthreads();
    float den = 0.f;
#pragma unroll 8
    for (int i = 0; i < NT; i++) den += ew[i];

    const int c = tid & 127, th = tid >> 7;
    float acc = 0.f;
    const float* xp = xt_ws + ((size_t)b * NT + th * 128) * NH + c;
#pragma unroll 4
    for (int i = 0; i < 128; i++) acc = fmaf(ew[th * 128 + i], xp[(size_t)i * NH], acc);
    pb[tid] = acc;
    __syncthreads();
    if (tid < NH) {
        float r = (pb[tid] + pb[tid + 128]) / den;
        if (sfx2) ((__hip_bfloat16*)out)[b * NH + tid] = __float2bfloat16(r);
        else      ((float*)out)[b * NH + tid] = r;
    }
}

extern "C" void kernel_launch(void* const* d_in, const int* in_sizes, int n_in,
                              void* d_out, int out_size, void* d_ws, size_t ws_size,
                              hipStream_t stream) {
    prep<<<5, 256, 0, stream>>>(
        d_in[1],
        d_in[2], d_in[3], d_in[4], d_in[5],
        d_in[6], d_in[7], d_in[8], d_in[9],
        d_in[10], d_in[11], d_in[12], d_in[13], d_in[14], d_in[15],
        d_in[16], d_in[17], d_in[18], d_in[19], d_in[20], d_in[21],
        d_in[22], d_in[23], d_in[24],
        d_ws);
    gcn_mfma<<<NBLKS, 256, 0, stream>>>(d_in[0], d_ws);
    float* F = (float*)d_ws;
    attn_pool<<<NB, 256, 0, stream>>>(d_in[0], F + FO_XT, F + FO_SC, d_out);
}

// Round 7
// 728.940 us; speedup vs baseline: 2.6075x; 1.2034x over previous
//
#include <hip/hip_runtime.h>
#include <hip/hip_bf16.h>
#include <math.h>

// TemporalSkeletonBranch — Round 7: adjacency mix on the matrix pipe.
// R6: VALUBusy 52%, MfmaUtil 3.9%, 4.9e7 bank conflicts -> epilogue gather/Yb
// round-trip dominates. R7: joints 25-32 are identity rows, edges live in 0..24
// -> z[0:25] = adj25@P via one K=32 MFMA (A = const 32x32 f16 adj, rows 25-31 = 0);
// identity rows come from live P C-frags. Yb eliminated; P staged as Pt[n][k]
// (B-layout, stride 40); hb stride 136, no XOR swizzle; tanh-gelu; 2 syncs/layer.

#define NJ 33
#define NF 52
#define NH 128
#define NT 256
#define NB 64
#define NSAMP (NB*NT)       // 16384
#define SPB 2               // samples per block
#define NBLKS (NSAMP/SPB)   // 8192
#define HSTR 136            // hb row stride (halves)
#define PSTR 40             // Pt k-stride (halves)

typedef unsigned short u16;
typedef _Float16 f16;
typedef f16   half8 __attribute__((ext_vector_type(8)));
typedef f16   h2    __attribute__((ext_vector_type(2)));
typedef float f32x4 __attribute__((ext_vector_type(4)));

// ---- workspace layout ----
#define HO_W0    0            // [n=128][k=64]
#define HO_S0    8192
#define HO_W1    16384        // [n=128][k=128]
#define HO_W2    32768
#define HO_TW1   49152
#define HO_ADJ32 65536        // [32][32] f16, rows/cols 25..31 = 0
#define H_TOTAL  66560
#define FO_BASE  (H_TOTAL/2)  // 33280 floats
#define FO_A0    (FO_BASE+0)  // [L*256 + {A:c, D:128+c}]
#define FO_SB0   (FO_BASE+768)
#define FO_TB1   (FO_BASE+896)
#define FO_TW2   (FO_BASE+1024)
#define FO_XT    (FO_BASE+1152)
#define FO_SC    (FO_XT + NSAMP*NH)

__device__ __forceinline__ float bf2f(u16 u) { return __uint_as_float(((unsigned)u) << 16); }
__device__ __forceinline__ float ldv(const void* p, long i, int f) {
    float r;
    if (f) r = bf2f(((const u16*)p)[i]);
    else   r = ((const float*)p)[i];
    return r;
}
__device__ int detect_bf16(const void* p) {
    const u16* q = (const u16*)p;
    int nz = 0, ok = 0;
#pragma unroll
    for (int k = 0; k < 64; k++) {
        u16 u = q[k];
        if (u & 0x7FFF) {
            nz++;
            int e = (u >> 7) & 0xFF;
            ok += (e >= 0x40 && e <= 0xBF) ? 1 : 0;
        }
    }
    return (nz == 0) || (ok * 20 >= nz * 19);
}

// tanh-form gelu (max err vs exact ~3e-4), exp2+rcp, overflow-clamped
__device__ __forceinline__ float gelu_t(float x) {
    float xc = fminf(fmaxf(x, -8.f), 8.f);
    float u  = xc * fmaf(xc * xc, 0.10294324f, 2.3022082f);
#if __has_builtin(__builtin_amdgcn_exp2f)
    float e  = __builtin_amdgcn_exp2f(u);
#else
    float e  = exp2f(u);
#endif
#if __has_builtin(__builtin_amdgcn_rcpf)
    float tt = (e - 1.f) * __builtin_amdgcn_rcpf(e + 1.f);
#else
    float tt = (e - 1.f) / (e + 1.f);
#endif
    float hx = 0.5f * x;
    return fmaf(hx, tt, hx);
}

#define MFMA16(a, b, c) __builtin_amdgcn_mfma_f32_16x16x32_f16(a, b, c, 0, 0, 0)

// ---- prep: dtype detect + fp16 transposed weights + folded BN + adj32 ----
__global__ __launch_bounds__(256) void prep(
    const void* adj,
    const void* W0, const void* b0, const void* S0, const void* sb0,
    const void* g0, const void* be0, const void* m0, const void* v0,
    const void* W1, const void* b1, const void* g1, const void* be1, const void* m1, const void* v1,
    const void* W2, const void* b2, const void* g2, const void* be2, const void* m2, const void* v2,
    const void* tW1, const void* tb1, const void* tW2,
    void* ws)
{
    f16* H = (f16*)ws; float* F = (float*)ws;
    const int bi = blockIdx.x, t = threadIdx.x;
    if (bi == 0) {
        const int fW = detect_bf16(W0), fS = detect_bf16(S0);
        for (int i = t; i < 128*64; i += 256) {
            int n = i >> 6, k = i & 63;
            H[HO_W0 + i] = (f16)(k < NF ? ldv(W0, (long)k*NH + n, fW) : 0.f);
            H[HO_S0 + i] = (f16)(k < NF ? ldv(S0, (long)k*NH + n, fS) : 0.f);
        }
    } else if (bi == 1) {
        const int f = detect_bf16(W1);
        for (int i = t; i < 128*128; i += 256) {
            int n = i >> 7, k = i & 127;
            H[HO_W1 + i] = (f16)ldv(W1, (long)k*NH + n, f);
        }
    } else if (bi == 2) {
        const int f = detect_bf16(W2);
        for (int i = t; i < 128*128; i += 256) {
            int n = i >> 7, k = i & 127;
            H[HO_W2 + i] = (f16)ldv(W2, (long)k*NH + n, f);
        }
    } else if (bi == 3) {
        const int f = detect_bf16(tW1);
        for (int i = t; i < 128*128; i += 256) {
            int n = i >> 7, k = i & 127;
            H[HO_TW1 + i] = (f16)ldv(tW1, (long)k*NH + n, f);
        }
    } else {
        if (t < 128) {
            int c = t;
            {
                float g = ldv(g0,c,detect_bf16(g0)), be = ldv(be0,c,detect_bf16(be0));
                float m = ldv(m0,c,detect_bf16(m0)), v = ldv(v0,c,detect_bf16(v0));
                float b = ldv(b0,c,detect_bf16(b0));
                float A = g * rsqrtf(v + 1e-5f);
                F[FO_A0 + 0*256 + c] = A; F[FO_A0 + 0*256 + 128 + c] = (b - m)*A + be;
            }
            {
                float g = ldv(g1,c,detect_bf16(g1)), be = ldv(be1,c,detect_bf16(be1));
                float m = ldv(m1,c,detect_bf16(m1)), v = ldv(v1,c,detect_bf16(v1));
                float b = ldv(b1,c,detect_bf16(b1));
                float A = g * rsqrtf(v + 1e-5f);
                F[FO_A0 + 1*256 + c] = A; F[FO_A0 + 1*256 + 128 + c] = (b - m)*A + be;
            }
            {
                float g = ldv(g2,c,detect_bf16(g2)), be = ldv(be2,c,detect_bf16(be2));
                float m = ldv(m2,c,detect_bf16(m2)), v = ldv(v2,c,detect_bf16(v2));
                float b = ldv(b2,c,detect_bf16(b2));
                float A = g * rsqrtf(v + 1e-5f);
                F[FO_A0 + 2*256 + c] = A; F[FO_A0 + 2*256 + 128 + c] = (b - m)*A + be;
            }
            F[FO_SB0 + c] = ldv(sb0, c, detect_bf16(sb0));
            F[FO_TB1 + c] = ldv(tb1, c, detect_bf16(tb1));
            F[FO_TW2 + c] = ldv(tW2, c, detect_bf16(tW2));
        }
        const int fA = detect_bf16(adj);
        for (int i = t; i < 1024; i += 256) {
            int r = i >> 5, c = i & 31;
            float v = (r < 25 && c < 25) ? ldv(adj, (long)r*NJ + c, fA) : 0.f;
            H[HO_ADJ32 + i] = (f16)v;
        }
    }
}

// ==== Pt write: P joint-rows 0..24 (C-frags) -> B-operand layout [n][k] ====
#define PTWRITE(ACC)                                                            \
    _Pragma("unroll")                                                           \
    for (int mt = 0; mt < 6; mt++) {                                            \
        const int sW = (mt >= 3) ? 1 : 0;                                       \
        const int jb = (mt - 3*sW) * 16;                                        \
        _Pragma("unroll")                                                       \
        for (int nt = 0; nt < 2; nt++) {                                        \
            f16* pp = Pt + sW*5120 + (nt ? c1 : c0)*PSTR;                       \
            _Pragma("unroll")                                                   \
            for (int r2 = 0; r2 < 4; r2 += 2) {                                 \
                int j0 = jb + q*4 + r2;                                         \
                if (j0 + 1 < 25) {                                              \
                    h2 v2w = { (f16)ACC[mt][nt][r2], (f16)ACC[mt][nt][r2+1] };  \
                    *(h2*)(pp + j0) = v2w;                                      \
                } else if (j0 < 25) {                                           \
                    pp[j0] = (f16)ACC[mt][nt][r2];                              \
                }                                                               \
            }                                                                   \
        }                                                                       \
    }

// ==== adjmix MFMA + elementwise epilogue (RMW hb), L = layer index ====
#define ADJEPI(L)                                                               \
    {                                                                           \
        half8 afadj0 = *(const half8*)(HW + HO_ADJ32 + ml*32 + q*8);            \
        half8 afadj1 = *(const half8*)(HW + HO_ADJ32 + (16+ml)*32 + q*8);       \
        half8 bfz[2][2];                                                        \
        _Pragma("unroll")                                                       \
        for (int sW = 0; sW < 2; sW++)                                          \
            _Pragma("unroll")                                                   \
            for (int nt = 0; nt < 2; nt++)                                      \
                bfz[sW][nt] = *(const half8*)(Pt + sW*5120 + (nt?c1:c0)*PSTR + q*8); \
        f32x4 zac[2][2][2];                                                     \
        _Pragma("unroll")                                                       \
        for (int sW = 0; sW < 2; sW++)                                          \
            _Pragma("unroll")                                                   \
            for (int nt = 0; nt < 2; nt++) {                                    \
                zac[sW][0][nt] = MFMA16(afadj0, bfz[sW][nt], z4);               \
                zac[sW][1][nt] = MFMA16(afadj1, bfz[sW][nt], z4);               \
            }                                                                   \
        _Pragma("unroll")                                                       \
        for (int nt = 0; nt < 2; nt++) {                                        \
            const int cc = nt ? c1 : c0;                                        \
            const float Av = F[FO_A0 + (L)*256 + cc];                           \
            const float Dv = F[FO_A0 + (L)*256 + 128 + cc];                     \
            _Pragma("unroll")                                                   \
            for (int sW = 0; sW < 2; sW++) {                                    \
                _Pragma("unroll")                                               \
                for (int m2 = 0; m2 < 2; m2++)                                  \
                    _Pragma("unroll")                                           \
                    for (int r4 = 0; r4 < 4; r4++) {                            \
                        int j = m2*16 + q*4 + r4;                               \
                        if (j < 25) {                                           \
                            int idx = (sW*48 + j)*HSTR + cc;                    \
                            float hv = (float)hb[idx];                          \
                            hb[idx] = (f16)(gelu_t(fmaf(zac[sW][m2][nt][r4], Av, Dv)) + hv); \
                        }                                                       \
                    }                                                           \
                _Pragma("unroll")                                               \
                for (int r4 = 0; r4 < 4; r4++) {                                \
                    int j = 16 + q*4 + r4;                                      \
                    if (j >= 25) {                                              \
                        int idx = (sW*48 + j)*HSTR + cc;                        \
                        float hv = (float)hb[idx];                              \
                        hb[idx] = (f16)(gelu_t(fmaf(acc[3*sW+1][nt][r4], Av, Dv)) + hv); \
                    }                                                           \
                }                                                               \
                if (q == 0) {                                                   \
                    int idx = (sW*48 + 32)*HSTR + cc;                           \
                    float hv = (float)hb[idx];                                  \
                    hb[idx] = (f16)(gelu_t(fmaf(acc[3*sW+2][nt][0], Av, Dv)) + hv); \
                }                                                               \
            }                                                                   \
        }                                                                       \
    }

// ==== main GEMM over K=128 weights ====
#define GEMM128(WOFF)                                                           \
    {                                                                           \
        half8 bf[2][4];                                                         \
        _Pragma("unroll")                                                       \
        for (int nt = 0; nt < 2; nt++)                                          \
            _Pragma("unroll")                                                   \
            for (int ks = 0; ks < 4; ks++)                                      \
                bf[nt][ks] = *(const half8*)(HW + (WOFF) + (nt?c1:c0)*128 + ks*32 + q*8); \
        _Pragma("unroll")                                                       \
        for (int mt = 0; mt < 6; mt++) { acc[mt][0] = z4; acc[mt][1] = z4; }    \
        _Pragma("unroll")                                                       \
        for (int mt = 0; mt < 6; mt++) {                                        \
            const int m = mt*16 + ml;                                           \
            _Pragma("unroll")                                                   \
            for (int ks = 0; ks < 4; ks++) {                                    \
                half8 af = *(const half8*)(hb + m*HSTR + ks*32 + q*8);          \
                acc[mt][0] = MFMA16(af, bf[0][ks], acc[mt][0]);                 \
                acc[mt][1] = MFMA16(af, bf[1][ks], acc[mt][1]);                 \
            }                                                                   \
        }                                                                       \
    }

__global__ __launch_bounds__(256) void gcn_mfma(const void* __restrict__ x,
                                                void* __restrict__ ws)
{
    const f16* HW = (const f16*)ws;
    float* F = (float*)ws;
    float* xt_g = F + FO_XT;
    float* sc_g = F + FO_SC;

    __shared__ __align__(16) f16 hb[96 * HSTR];     // 26.1 KB
    __shared__ __align__(16) f16 Pt[2 * 128 * PSTR];// 20.5 KB
    __shared__ float sTB1[128], sTW2[128];
    __shared__ int sfx;
    float* xtb  = (float*)Pt;        // alias (tail only, barrier-separated)
    float* rbuf = (float*)Pt + 256;

    const int t = threadIdx.x, lane = t & 63, wv = t >> 6;
    const int q = lane >> 4, ml = lane & 15;
    const int n0 = wv * 32;
    const int c0 = n0 + ml, c1 = n0 + 16 + ml;
    const f32x4 z4 = {0.f, 0.f, 0.f, 0.f};

    if (t == 0) sfx = detect_bf16(x);
    if (t < 128) { sTB1[t] = F[FO_TB1 + t]; sTW2[t] = F[FO_TW2 + t]; }
    for (int i = t; i < 2048; i += 256) {          // zero Pt k = 24..31
        int sW = i >> 10, n = (i >> 3) & 127, k = 24 + (i & 7);
        Pt[sW*5120 + n*PSTR + k] = (f16)0.f;
    }
    __syncthreads();

    // ---- stage x -> hb rows j<33 per sample (frame stride 48), K=64 region ----
    {
        const int fX = sfx;
        const long xb = (long)blockIdx.x * (SPB * NJ * NF);
#pragma unroll 1
        for (int it = 0; it < 3; it++) {
            int g = t + it * 256;
            if (g < 66 * 8) {
                int r = g >> 3, blk = g & 7;
                int fr = (r < 33) ? r : r + 15;
                long rb = xb + (long)r * NF;
                half8 o;
#pragma unroll
                for (int i = 0; i < 8; i++) {
                    int cx = blk * 8 + i;
                    o[i] = (f16)(cx < NF ? ldv(x, rb + cx, fX) : 0.f);
                }
                *(half8*)(hb + fr * HSTR + blk * 8) = o;
            }
        }
    }
    __syncthreads();

    f32x4 acc[6][2];

    // ================= layer 0 (K=64): P = x@W0, skip = x@S0 =================
    {
        half8 bw[2][2], bs[2][2];
#pragma unroll
        for (int nt = 0; nt < 2; nt++) {
            int n = nt ? c1 : c0;
#pragma unroll
            for (int ks = 0; ks < 2; ks++) {
                bw[nt][ks] = *(const half8*)(HW + HO_W0 + n*64 + ks*32 + q*8);
                bs[nt][ks] = *(const half8*)(HW + HO_S0 + n*64 + ks*32 + q*8);
            }
        }
        f32x4 acs[6][2];
#pragma unroll
        for (int mt = 0; mt < 6; mt++) { acc[mt][0]=z4; acc[mt][1]=z4; acs[mt][0]=z4; acs[mt][1]=z4; }
#pragma unroll
        for (int mt = 0; mt < 6; mt++) {
            const int m = mt*16 + ml;
            half8 a0 = *(const half8*)(hb + m*HSTR + q*8);
            half8 a1 = *(const half8*)(hb + m*HSTR + 32 + q*8);
            acc[mt][0] = MFMA16(a0, bw[0][0], acc[mt][0]);
            acc[mt][0] = MFMA16(a1, bw[0][1], acc[mt][0]);
            acc[mt][1] = MFMA16(a0, bw[1][0], acc[mt][1]);
            acc[mt][1] = MFMA16(a1, bw[1][1], acc[mt][1]);
            acs[mt][0] = MFMA16(a0, bs[0][0], acs[mt][0]);
            acs[mt][0] = MFMA16(a1, bs[0][1], acs[mt][0]);
            acs[mt][1] = MFMA16(a0, bs[1][0], acs[mt][1]);
            acs[mt][1] = MFMA16(a1, bs[1][1], acs[mt][1]);
        }
        __syncthreads();               // all x A-reads done before hb/Pt writes
        PTWRITE(acc)
        // skip + sb0 -> hb (h_prev for the L0 epilogue); clobbers x region
        const float sb0a = F[FO_SB0 + c0], sb0b = F[FO_SB0 + c1];
#pragma unroll
        for (int mt = 0; mt < 6; mt++) {
            const int sW = (mt >= 3) ? 1 : 0;
            const int jb = (mt - 3*sW) * 16;
#pragma unroll
            for (int nt = 0; nt < 2; nt++) {
                const int cc = nt ? c1 : c0;
                const float sbv = nt ? sb0b : sb0a;
#pragma unroll
                for (int r4 = 0; r4 < 4; r4++) {
                    int j = jb + q*4 + r4;
                    if (j < 33)
                        hb[(sW*48 + j)*HSTR + cc] = (f16)(acs[mt][nt][r4] + sbv);
                }
            }
        }
        ADJEPI(0)
        __syncthreads();
    }

    // ================= layer 1 =================
    GEMM128(HO_W1)
    __syncthreads();
    PTWRITE(acc)
    ADJEPI(1)
    __syncthreads();

    // ================= layer 2 =================
    GEMM128(HO_W2)
    __syncthreads();
    PTWRITE(acc)
    ADJEPI(2)
    __syncthreads();

    // ================= mean over joints + attention score MLP =================
    {
        const int sW = t >> 7, c = t & 127;
        float sum = 0.f;
#pragma unroll
        for (int j = 0; j < NJ; j++)
            sum += (float)hb[(sW*48 + j)*HSTR + c];
        float xtc = sum * (1.0f / 33.0f);
        xt_g[((long)blockIdx.x * SPB + sW) * NH + c] = xtc;
        xtb[t] = xtc;
        __syncthreads();

        float u = 0.f;
#pragma unroll
        for (int kk = 0; kk < 16; kk++) {
            half8 wv8 = *(const half8*)(HW + HO_TW1 + c*128 + kk*8);
#pragma unroll
            for (int i = 0; i < 8; i++)
                u = fmaf(xtb[sW*128 + kk*8 + i], (float)wv8[i], u);
        }
        rbuf[t] = gelu_t(u + sTB1[c]) * sTW2[c];   // tb2 omitted: softmax shift-invariant
        __syncthreads();
#pragma unroll
        for (int st = 64; st > 0; st >>= 1) {
            if ((t & 127) < st) rbuf[t] += rbuf[t + st];
            __syncthreads();
        }
        if ((t & 127) == 0) sc_g[blockIdx.x * SPB + sW] = rbuf[t];
    }
}

// ---- softmax over T + weighted sum -> out[B,H]; 256 blocks (b x channel-quarter) ----
__global__ __launch_bounds__(256) void attn_pool(
    const void* __restrict__ x,
    const float* __restrict__ xt_ws, const float* __restrict__ score_ws,
    void* __restrict__ out)
{
    __shared__ float sc[NT];
    __shared__ float ew[NT];
    __shared__ float pb[256];
    __shared__ int sfx2;
    const int t = threadIdx.x;
    const int b = blockIdx.x >> 2, qr = blockIdx.x & 3;

    if (t == 0) sfx2 = detect_bf16(x);
    sc[t] = score_ws[b * NT + t];
    __syncthreads();
    float mx = -1e30f;
#pragma unroll 8
    for (int i = 0; i < NT; i++) mx = fmaxf(mx, sc[i]);
    ew[t] = __expf(sc[t] - mx);
    __syncthreads();
    float den = 0.f;
#pragma unroll 8
    for (int i = 0; i < NT; i++) den += ew[i];

    const int cl = t & 31, ch = t >> 5;
    const int c = qr * 32 + cl;
    float a = 0.f;
#pragma unroll 4
    for (int i = ch * 32; i < ch * 32 + 32; i++)
        a = fmaf(ew[i], xt_ws[((long)b * NT + i) * NH + c], a);
    pb[t] = a;
    __syncthreads();
    if (t < 128) pb[t] += pb[t + 128];
    __syncthreads();
    if (t < 64) pb[t] += pb[t + 64];
    __syncthreads();
    if (t < 32) {
        float r = (pb[t] + pb[t + 32]) / den;
        if (sfx2) ((__hip_bfloat16*)out)[b * NH + qr * 32 + t] = __float2bfloat16(r);
        else      ((float*)out)[b * NH + qr * 32 + t] = r;
    }
}

extern "C" void kernel_launch(void* const* d_in, const int* in_sizes, int n_in,
                              void* d_out, int out_size, void* d_ws, size_t ws_size,
                              hipStream_t stream) {
    prep<<<5, 256, 0, stream>>>(
        d_in[1],
        d_in[2], d_in[3], d_in[4], d_in[5],
        d_in[6], d_in[7], d_in[8], d_in[9],
        d_in[10], d_in[11], d_in[12], d_in[13], d_in[14], d_in[15],
        d_in[16], d_in[17], d_in[18], d_in[19], d_in[20], d_in[21],
        d_in[22], d_in[23], d_in[24],
        d_ws);
    gcn_mfma<<<NBLKS, 256, 0, stream>>>(d_in[0], d_ws);
    float* F = (float*)d_ws;
    attn_pool<<<NB * 4, 256, 0, stream>>>(d_in[0], F + FO_XT, F + FO_SC, d_out);
}

// Round 8
// 608.357 us; speedup vs baseline: 3.1243x; 1.1982x over previous
//
#include <hip/hip_runtime.h>
#include <hip/hip_bf16.h>
#include <math.h>

// TemporalSkeletonBranch — Round 8: register-carried h across layers.
// R7 (527us): VALU 44% dominated by epilogue LDS RMW of h + skip-store + dead
// PTWRITE rows; ~195us fixed gap from prep/attn_pool serial loops.
// R8: h stays in regs (C-frag position mapping identical across layers);
// L0 skip from acs regs; L2 epilogue writes nothing to hb; mean from regs via
// shfl; PTWRITE mt2/5 dropped; attn_pool shuffle reductions; prep coalesced loads.

#define NJ 33
#define NF 52
#define NH 128
#define NT 256
#define NB 64
#define NSAMP (NB*NT)       // 16384
#define SPB 2               // samples per block
#define NBLKS (NSAMP/SPB)   // 8192
#define HSTR 136            // hb row stride (halves)
#define PSTR 40             // Pt k-stride (halves)

typedef unsigned short u16;
typedef _Float16 f16;
typedef f16   half8 __attribute__((ext_vector_type(8)));
typedef f16   h2    __attribute__((ext_vector_type(2)));
typedef float f32x4 __attribute__((ext_vector_type(4)));

// ---- workspace layout ----
#define HO_W0    0            // [n=128][k=64]
#define HO_S0    8192
#define HO_W1    16384        // [n=128][k=128]
#define HO_W2    32768
#define HO_TW1   49152
#define HO_ADJ32 65536        // [32][32] f16, rows/cols 25..31 = 0
#define H_TOTAL  66560
#define FO_BASE  (H_TOTAL/2)  // 33280 floats
#define FO_A0    (FO_BASE+0)  // [L*256 + {A:c, D:128+c}]
#define FO_SB0   (FO_BASE+768)
#define FO_TB1   (FO_BASE+896)
#define FO_TW2   (FO_BASE+1024)
#define FO_XT    (FO_BASE+1152)
#define FO_SC    (FO_XT + NSAMP*NH)

__device__ __forceinline__ float bf2f(u16 u) { return __uint_as_float(((unsigned)u) << 16); }
__device__ __forceinline__ float ldv(const void* p, long i, int f) {
    float r;
    if (f) r = bf2f(((const u16*)p)[i]);
    else   r = ((const float*)p)[i];
    return r;
}
__device__ int detect_bf16(const void* p) {
    const u16* q = (const u16*)p;
    int nz = 0, ok = 0;
#pragma unroll
    for (int k = 0; k < 64; k++) {
        u16 u = q[k];
        if (u & 0x7FFF) {
            nz++;
            int e = (u >> 7) & 0xFF;
            ok += (e >= 0x40 && e <= 0xBF) ? 1 : 0;
        }
    }
    return (nz == 0) || (ok * 20 >= nz * 19);
}

// tanh-form gelu (max err ~3e-4), exp2+rcp, overflow-clamped
__device__ __forceinline__ float gelu_t(float x) {
    float xc = fminf(fmaxf(x, -8.f), 8.f);
    float u  = xc * fmaf(xc * xc, 0.10294324f, 2.3022082f);
#if __has_builtin(__builtin_amdgcn_exp2f)
    float e  = __builtin_amdgcn_exp2f(u);
#else
    float e  = exp2f(u);
#endif
#if __has_builtin(__builtin_amdgcn_rcpf)
    float tt = (e - 1.f) * __builtin_amdgcn_rcpf(e + 1.f);
#else
    float tt = (e - 1.f) / (e + 1.f);
#endif
    float hx = 0.5f * x;
    return fmaf(hx, tt, hx);
}

#define MFMA16(a, b, c) __builtin_amdgcn_mfma_f32_16x16x32_f16(a, b, c, 0, 0, 0)

// ---- prep: dtype detect + fp16 transposed weights + folded BN + adj32 ----
// Transposes now read coalesced (i = k*N + n consecutive) and store strided.
__global__ __launch_bounds__(256) void prep(
    const void* adj,
    const void* W0, const void* b0, const void* S0, const void* sb0,
    const void* g0, const void* be0, const void* m0, const void* v0,
    const void* W1, const void* b1, const void* g1, const void* be1, const void* m1, const void* v1,
    const void* W2, const void* b2, const void* g2, const void* be2, const void* m2, const void* v2,
    const void* tW1, const void* tb1, const void* tW2,
    void* ws)
{
    f16* H = (f16*)ws; float* F = (float*)ws;
    const int bi = blockIdx.x, t = threadIdx.x;
    if (bi == 0) {
        const int fW = detect_bf16(W0), fS = detect_bf16(S0);
        for (int i = t; i < NF * 128; i += 256) {
            int k = i >> 7, n = i & 127;
            H[HO_W0 + n * 64 + k] = (f16)ldv(W0, i, fW);
            H[HO_S0 + n * 64 + k] = (f16)ldv(S0, i, fS);
        }
        for (int i = t; i < 128 * 16; i += 256) {     // zero pad k = 52..63
            int n = i >> 4, k = 48 + (i & 15);
            if (k >= NF) { H[HO_W0 + n * 64 + k] = (f16)0.f; H[HO_S0 + n * 64 + k] = (f16)0.f; }
        }
    } else if (bi == 1) {
        const int f = detect_bf16(W1);
        for (int i = t; i < 128 * 128; i += 256) {
            int k = i >> 7, n = i & 127;
            H[HO_W1 + n * 128 + k] = (f16)ldv(W1, i, f);
        }
    } else if (bi == 2) {
        const int f = detect_bf16(W2);
        for (int i = t; i < 128 * 128; i += 256) {
            int k = i >> 7, n = i & 127;
            H[HO_W2 + n * 128 + k] = (f16)ldv(W2, i, f);
        }
    } else if (bi == 3) {
        const int f = detect_bf16(tW1);
        for (int i = t; i < 128 * 128; i += 256) {
            int k = i >> 7, n = i & 127;
            H[HO_TW1 + n * 128 + k] = (f16)ldv(tW1, i, f);
        }
    } else {
        if (t < 128) {
            int c = t;
            {
                float g = ldv(g0,c,detect_bf16(g0)), be = ldv(be0,c,detect_bf16(be0));
                float m = ldv(m0,c,detect_bf16(m0)), v = ldv(v0,c,detect_bf16(v0));
                float b = ldv(b0,c,detect_bf16(b0));
                float A = g * rsqrtf(v + 1e-5f);
                F[FO_A0 + 0*256 + c] = A; F[FO_A0 + 0*256 + 128 + c] = (b - m)*A + be;
            }
            {
                float g = ldv(g1,c,detect_bf16(g1)), be = ldv(be1,c,detect_bf16(be1));
                float m = ldv(m1,c,detect_bf16(m1)), v = ldv(v1,c,detect_bf16(v1));
                float b = ldv(b1,c,detect_bf16(b1));
                float A = g * rsqrtf(v + 1e-5f);
                F[FO_A0 + 1*256 + c] = A; F[FO_A0 + 1*256 + 128 + c] = (b - m)*A + be;
            }
            {
                float g = ldv(g2,c,detect_bf16(g2)), be = ldv(be2,c,detect_bf16(be2));
                float m = ldv(m2,c,detect_bf16(m2)), v = ldv(v2,c,detect_bf16(v2));
                float b = ldv(b2,c,detect_bf16(b2));
                float A = g * rsqrtf(v + 1e-5f);
                F[FO_A0 + 2*256 + c] = A; F[FO_A0 + 2*256 + 128 + c] = (b - m)*A + be;
            }
            F[FO_SB0 + c] = ldv(sb0, c, detect_bf16(sb0));
            F[FO_TB1 + c] = ldv(tb1, c, detect_bf16(tb1));
            F[FO_TW2 + c] = ldv(tW2, c, detect_bf16(tW2));
        }
        const int fA = detect_bf16(adj);
        for (int i = t; i < 1024; i += 256) {
            int r = i >> 5, c = i & 31;
            float v = (r < 25 && c < 25) ? ldv(adj, (long)r*NJ + c, fA) : 0.f;
            H[HO_ADJ32 + i] = (f16)v;
        }
    }
}

// ==== Pt write: P joint-rows 0..24 (C-frags) -> B-layout [n][k]; mt 2/5 dead ====
#define PTWRITE(ACC)                                                            \
    _Pragma("unroll")                                                           \
    for (int mt = 0; mt < 6; mt++) {                                            \
        if (mt != 2 && mt != 5) {                                               \
            const int sW = (mt >= 3) ? 1 : 0;                                   \
            const int jb = (mt - 3*sW) * 16;                                    \
            _Pragma("unroll")                                                   \
            for (int nt = 0; nt < 2; nt++) {                                    \
                f16* pp = Pt + sW*5120 + (nt ? c1 : c0)*PSTR;                   \
                _Pragma("unroll")                                               \
                for (int r2 = 0; r2 < 4; r2 += 2) {                             \
                    int j0 = jb + q*4 + r2;                                     \
                    if (j0 + 1 < 25) {                                          \
                        h2 v2w = { (f16)ACC[mt][nt][r2], (f16)ACC[mt][nt][r2+1] }; \
                        *(h2*)(pp + j0) = v2w;                                  \
                    } else if (j0 < 25) {                                       \
                        pp[j0] = (f16)ACC[mt][nt][r2];                          \
                    }                                                           \
                }                                                               \
            }                                                                   \
        }                                                                       \
    }

// ==== adjmix MFMA + register epilogue: hz/h32 updated in place ====
#define ADJEPI(L, ISL0, WRHB) {                                                 \
    half8 afadj0 = *(const half8*)(HW + HO_ADJ32 + ml*32 + q*8);                \
    half8 afadj1 = *(const half8*)(HW + HO_ADJ32 + (16+ml)*32 + q*8);           \
    f32x4 zac[2][2][2];                                                         \
    _Pragma("unroll")                                                           \
    for (int sW = 0; sW < 2; sW++) {                                            \
        _Pragma("unroll")                                                       \
        for (int nt = 0; nt < 2; nt++) {                                        \
            half8 bz = *(const half8*)(Pt + sW*5120 + (nt?c1:c0)*PSTR + q*8);   \
            zac[sW][0][nt] = MFMA16(afadj0, bz, z4);                            \
            zac[sW][1][nt] = MFMA16(afadj1, bz, z4);                            \
        }                                                                       \
    }                                                                           \
    _Pragma("unroll")                                                           \
    for (int nt = 0; nt < 2; nt++) {                                            \
        const int cc = nt ? c1 : c0;                                            \
        const float Av = rA[L][nt], Dv = rD[L][nt];                             \
        const float sbv = nt ? sb0b : sb0a;                                     \
        _Pragma("unroll")                                                       \
        for (int sW = 0; sW < 2; sW++) {                                        \
            _Pragma("unroll")                                                   \
            for (int m2 = 0; m2 < 2; m2++) {                                    \
                _Pragma("unroll")                                               \
                for (int r4 = 0; r4 < 4; r4++) {                                \
                    float zv = (m2 == 0) ? zac[sW][0][nt][r4]                   \
                             : (jlt[r4] ? zac[sW][1][nt][r4]                    \
                                        : acc[3*sW+1][nt][r4]);                 \
                    float hold = (ISL0) ? (acs[3*sW+m2][nt][r4] + sbv)          \
                                        : hz[sW][m2][nt][r4];                   \
                    float hnew = gelu_t(fmaf(zv, Av, Dv)) + hold;               \
                    hz[sW][m2][nt][r4] = hnew;                                  \
                    if (WRHB)                                                   \
                        hb[(sW*48 + m2*16 + q*4 + r4)*HSTR + cc] = (f16)hnew;   \
                }                                                               \
            }                                                                   \
            {                                                                   \
                float zv = acc[3*sW+2][nt][0];                                  \
                float hold = (ISL0) ? (acs[3*sW+2][nt][0] + sbv)                \
                                    : h32[sW][nt];                              \
                float hnew = gelu_t(fmaf(zv, Av, Dv)) + hold;                   \
                h32[sW][nt] = (q == 0) ? hnew : 0.f;                            \
                if (WRHB && q == 0)                                             \
                    hb[(sW*48 + 32)*HSTR + cc] = (f16)hnew;                     \
            }                                                                   \
        }                                                                       \
    }                                                                           \
}

// ==== main GEMM over K=128 weights ====
#define GEMM128(WOFF)                                                           \
    {                                                                           \
        half8 bf[2][4];                                                         \
        _Pragma("unroll")                                                       \
        for (int nt = 0; nt < 2; nt++)                                          \
            _Pragma("unroll")                                                   \
            for (int ks = 0; ks < 4; ks++)                                      \
                bf[nt][ks] = *(const half8*)(HW + (WOFF) + (nt?c1:c0)*128 + ks*32 + q*8); \
        _Pragma("unroll")                                                       \
        for (int mt = 0; mt < 6; mt++) { acc[mt][0] = z4; acc[mt][1] = z4; }    \
        _Pragma("unroll")                                                       \
        for (int mt = 0; mt < 6; mt++) {                                        \
            const int m = mt*16 + ml;                                           \
            _Pragma("unroll")                                                   \
            for (int ks = 0; ks < 4; ks++) {                                    \
                half8 af = *(const half8*)(hb + m*HSTR + ks*32 + q*8);          \
                acc[mt][0] = MFMA16(af, bf[0][ks], acc[mt][0]);                 \
                acc[mt][1] = MFMA16(af, bf[1][ks], acc[mt][1]);                 \
            }                                                                   \
        }                                                                       \
    }

__global__ __launch_bounds__(256) void gcn_mfma(const void* __restrict__ x,
                                                void* __restrict__ ws)
{
    const f16* HW = (const f16*)ws;
    float* F = (float*)ws;
    float* xt_g = F + FO_XT;
    float* sc_g = F + FO_SC;

    __shared__ __align__(16) f16 hb[96 * HSTR];       // 26.1 KB
    __shared__ __align__(16) f16 Pt[2 * 128 * PSTR];  // 20.5 KB
    __shared__ float sTB1[128], sTW2[128];
    __shared__ float rbuf4[4];
    __shared__ int sfx;
    float* xtb = (float*)Pt;        // alias; used only after ADJEPI(2)+sync

    const int t = threadIdx.x, lane = t & 63, wv = t >> 6;
    const int q = lane >> 4, ml = lane & 15;
    const int n0 = wv * 32;
    const int c0 = n0 + ml, c1 = n0 + 16 + ml;
    const f32x4 z4 = {0.f, 0.f, 0.f, 0.f};
    const bool jlt[4] = { q <= 2, q <= 1, q <= 1, q <= 1 };   // 16+q*4+r4 < 25

    if (t == 0) sfx = detect_bf16(x);
    if (t < 128) { sTB1[t] = F[FO_TB1 + t]; sTW2[t] = F[FO_TW2 + t]; }
    for (int i = t; i < 2048; i += 256) {             // zero Pt k = 24..31
        int sW = i >> 10, n = (i >> 3) & 127, k = 24 + (i & 7);
        Pt[sW*5120 + n*PSTR + k] = (f16)0.f;
    }

    // hoisted per-channel constants
    float rA[3][2], rD[3][2];
#pragma unroll
    for (int L = 0; L < 3; L++) {
        rA[L][0] = F[FO_A0 + L*256 + c0];        rA[L][1] = F[FO_A0 + L*256 + c1];
        rD[L][0] = F[FO_A0 + L*256 + 128 + c0];  rD[L][1] = F[FO_A0 + L*256 + 128 + c1];
    }
    const float sb0a = F[FO_SB0 + c0], sb0b = F[FO_SB0 + c1];
    __syncthreads();

    // ---- stage x -> hb rows j<33 per frame (stride 48), K=64 region ----
    {
        const int fX = sfx;
        const long xb = (long)blockIdx.x * (SPB * NJ * NF);
#pragma unroll 1
        for (int it = 0; it < 3; it++) {
            int g = t + it * 256;
            if (g < 66 * 8) {
                int r = g >> 3, blk = g & 7;
                int fr = (r < 33) ? r : r + 15;
                long rb = xb + (long)r * NF;
                half8 o;
#pragma unroll
                for (int i = 0; i < 8; i++) {
                    int cx = blk * 8 + i;
                    o[i] = (f16)(cx < NF ? ldv(x, rb + cx, fX) : 0.f);
                }
                *(half8*)(hb + fr * HSTR + blk * 8) = o;
            }
        }
    }
    __syncthreads();

    f32x4 acc[6][2];
    f32x4 acs[6][2];
    float hz[2][2][2][4];   // [sW][m2][nt][r4] — h carried in registers
    float h32[2][2];

    // ================= layer 0 (K=64): P = x@W0, skip = x@S0 =================
    {
        half8 bw[2][2], bs[2][2];
#pragma unroll
        for (int nt = 0; nt < 2; nt++) {
            int n = nt ? c1 : c0;
#pragma unroll
            for (int ks = 0; ks < 2; ks++) {
                bw[nt][ks] = *(const half8*)(HW + HO_W0 + n*64 + ks*32 + q*8);
                bs[nt][ks] = *(const half8*)(HW + HO_S0 + n*64 + ks*32 + q*8);
            }
        }
#pragma unroll
        for (int mt = 0; mt < 6; mt++) { acc[mt][0]=z4; acc[mt][1]=z4; acs[mt][0]=z4; acs[mt][1]=z4; }
#pragma unroll
        for (int mt = 0; mt < 6; mt++) {
            const int m = mt*16 + ml;
            half8 a0 = *(const half8*)(hb + m*HSTR + q*8);
            half8 a1 = *(const half8*)(hb + m*HSTR + 32 + q*8);
            acc[mt][0] = MFMA16(a0, bw[0][0], acc[mt][0]);
            acc[mt][0] = MFMA16(a1, bw[0][1], acc[mt][0]);
            acc[mt][1] = MFMA16(a0, bw[1][0], acc[mt][1]);
            acc[mt][1] = MFMA16(a1, bw[1][1], acc[mt][1]);
            acs[mt][0] = MFMA16(a0, bs[0][0], acs[mt][0]);
            acs[mt][0] = MFMA16(a1, bs[0][1], acs[mt][0]);
            acs[mt][1] = MFMA16(a0, bs[1][0], acs[mt][1]);
            acs[mt][1] = MFMA16(a1, bs[1][1], acs[mt][1]);
        }
        __syncthreads();               // all x A-reads done before hb/Pt writes
        PTWRITE(acc)
        ADJEPI(0, 1, 1)
        __syncthreads();
    }

    // ================= layer 1 =================
    GEMM128(HO_W1)
    __syncthreads();
    PTWRITE(acc)
    ADJEPI(1, 0, 1)
    __syncthreads();

    // ================= layer 2 (no hb writes needed) =================
    GEMM128(HO_W2)
    __syncthreads();
    PTWRITE(acc)
    ADJEPI(2, 0, 0)
    __syncthreads();                   // Pt reads done before xtb alias writes

    // ================= mean over joints (from regs) + score MLP =================
#pragma unroll
    for (int sW = 0; sW < 2; sW++)
#pragma unroll
        for (int nt = 0; nt < 2; nt++) {
            float s = h32[sW][nt];
#pragma unroll
            for (int m2 = 0; m2 < 2; m2++)
#pragma unroll
                for (int r4 = 0; r4 < 4; r4++) s += hz[sW][m2][nt][r4];
            s += __shfl_xor(s, 16, 64);
            s += __shfl_xor(s, 32, 64);
            float xtc = s * (1.0f / 33.0f);
            if (q == 0) {
                int cc = nt ? c1 : c0;
                xtb[sW * 128 + cc] = xtc;
                xt_g[((long)blockIdx.x * SPB + sW) * NH + cc] = xtc;
            }
        }
    __syncthreads();

    {
        const int sW = t >> 7, c = t & 127;
        float u = 0.f;
#pragma unroll
        for (int kk = 0; kk < 16; kk++) {
            half8 wv8 = *(const half8*)(HW + HO_TW1 + c*128 + kk*8);
#pragma unroll
            for (int i = 0; i < 8; i++)
                u = fmaf(xtb[sW*128 + kk*8 + i], (float)wv8[i], u);
        }
        float r = gelu_t(u + sTB1[c]) * sTW2[c];   // tb2 omitted: softmax shift-invariant
#pragma unroll
        for (int off = 32; off > 0; off >>= 1) r += __shfl_xor(r, off, 64);
        if (lane == 0) rbuf4[wv] = r;
        __syncthreads();
        if (t == 0) {
            sc_g[blockIdx.x * SPB + 0] = rbuf4[0] + rbuf4[1];
            sc_g[blockIdx.x * SPB + 1] = rbuf4[2] + rbuf4[3];
        }
    }
}

// ---- softmax over T + weighted sum -> out[B,H]; shuffle reductions ----
__global__ __launch_bounds__(256) void attn_pool(
    const void* __restrict__ x,
    const float* __restrict__ xt_ws, const float* __restrict__ score_ws,
    void* __restrict__ out)
{
    __shared__ float ew[NT];
    __shared__ float red[8];
    __shared__ float pb[256];
    __shared__ int sfx2;
    const int t = threadIdx.x, lane = t & 63, wv = t >> 6;
    const int b = blockIdx.x >> 2, qr = blockIdx.x & 3;

    if (t == 0) sfx2 = detect_bf16(x);
    float sv = score_ws[b * NT + t];
    float m = sv;
#pragma unroll
    for (int off = 32; off > 0; off >>= 1) m = fmaxf(m, __shfl_xor(m, off, 64));
    if (lane == 0) red[wv] = m;
    __syncthreads();
    float mx = fmaxf(fmaxf(red[0], red[1]), fmaxf(red[2], red[3]));
    float e = __expf(sv - mx);
    ew[t] = e;
    float d = e;
#pragma unroll
    for (int off = 32; off > 0; off >>= 1) d += __shfl_xor(d, off, 64);
    if (lane == 0) red[4 + wv] = d;
    __syncthreads();
    float den = red[4] + red[5] + red[6] + red[7];

    const int cl = t & 31, ch = t >> 5;
    const int c = qr * 32 + cl;
    float a = 0.f;
#pragma unroll 4
    for (int i = ch * 32; i < ch * 32 + 32; i++)
        a = fmaf(ew[i], xt_ws[((long)b * NT + i) * NH + c], a);
    pb[t] = a;
    __syncthreads();
    if (t < 128) pb[t] += pb[t + 128];
    __syncthreads();
    if (t < 64) pb[t] += pb[t + 64];
    __syncthreads();
    if (t < 32) {
        float r = (pb[t] + pb[t + 32]) / den;
        if (sfx2) ((__hip_bfloat16*)out)[b * NH + qr * 32 + t] = __float2bfloat16(r);
        else      ((float*)out)[b * NH + qr * 32 + t] = r;
    }
}

extern "C" void kernel_launch(void* const* d_in, const int* in_sizes, int n_in,
                              void* d_out, int out_size, void* d_ws, size_t ws_size,
                              hipStream_t stream) {
    prep<<<5, 256, 0, stream>>>(
        d_in[1],
        d_in[2], d_in[3], d_in[4], d_in[5],
        d_in[6], d_in[7], d_in[8], d_in[9],
        d_in[10], d_in[11], d_in[12], d_in[13], d_in[14], d_in[15],
        d_in[16], d_in[17], d_in[18], d_in[19], d_in[20], d_in[21],
        d_in[22], d_in[23], d_in[24],
        d_ws);
    gcn_mfma<<<NBLKS, 256, 0, stream>>>(d_in[0], d_ws);
    float* F = (float*)d_ws;
    attn_pool<<<NB * 4, 256, 0, stream>>>(d_in[0], F + FO_XT, F + FO_SC, d_out);
}

// Round 9
// 576.871 us; speedup vs baseline: 3.2949x; 1.0546x over previous
//
#include <hip/hip_runtime.h>
#include <hip/hip_bf16.h>
#include <math.h>

// TemporalSkeletonBranch — Round 9: dense M-packing (5 tiles, 4 fully dense).
// R8 (444us): 54% issue-idle at 8 waves/CU; 6 M-tiles for 66 rows (25% MFMA waste);
// LDS 47KB at the 2-block boundary. R9: frame0 j0-31 -> rows 0-31, frame1 -> 32-63,
// j32 pair -> rows 64/65 of tile 4. -17% MFMA/A-reads; LDS ~42.3KB -> 3 blocks/CU.

#define NJ 33
#define NF 52
#define NH 128
#define NT 256
#define NB 64
#define NSAMP (NB*NT)       // 16384
#define SPB 2               // samples per block
#define NBLKS (NSAMP/SPB)   // 8192
#define HSTR 136            // hb row stride (halves)
#define PSTR 40             // Pt k-stride (halves, 16B-aligned for b128)

typedef unsigned short u16;
typedef _Float16 f16;
typedef f16   half8 __attribute__((ext_vector_type(8)));
typedef f16   h2    __attribute__((ext_vector_type(2)));
typedef float f32x4 __attribute__((ext_vector_type(4)));

// ---- workspace layout (R8-proven) ----
#define HO_W0    0            // [n=128][k=64]
#define HO_S0    8192
#define HO_W1    16384        // [n=128][k=128]
#define HO_W2    32768
#define HO_TW1   49152
#define HO_ADJ32 65536        // [32][32] f16, rows/cols 25..31 = 0
#define H_TOTAL  66560
#define FO_BASE  (H_TOTAL/2)  // 33280 floats
#define FO_A0    (FO_BASE+0)  // [L*256 + {A:c, D:128+c}]
#define FO_SB0   (FO_BASE+768)
#define FO_TB1   (FO_BASE+896)
#define FO_TW2   (FO_BASE+1024)
#define FO_XT    (FO_BASE+1152)
#define FO_SC    (FO_XT + NSAMP*NH)

__device__ __forceinline__ float bf2f(u16 u) { return __uint_as_float(((unsigned)u) << 16); }
__device__ __forceinline__ float ldv(const void* p, long i, int f) {
    float r;
    if (f) r = bf2f(((const u16*)p)[i]);
    else   r = ((const float*)p)[i];
    return r;
}
__device__ int detect_bf16(const void* p) {
    const u16* q = (const u16*)p;
    int nz = 0, ok = 0;
#pragma unroll
    for (int k = 0; k < 64; k++) {
        u16 u = q[k];
        if (u & 0x7FFF) {
            nz++;
            int e = (u >> 7) & 0xFF;
            ok += (e >= 0x40 && e <= 0xBF) ? 1 : 0;
        }
    }
    return (nz == 0) || (ok * 20 >= nz * 19);
}

// tanh-form gelu (max err ~3e-4), exp2+rcp, overflow-clamped
__device__ __forceinline__ float gelu_t(float x) {
    float xc = fminf(fmaxf(x, -8.f), 8.f);
    float u  = xc * fmaf(xc * xc, 0.10294324f, 2.3022082f);
#if __has_builtin(__builtin_amdgcn_exp2f)
    float e  = __builtin_amdgcn_exp2f(u);
#else
    float e  = exp2f(u);
#endif
#if __has_builtin(__builtin_amdgcn_rcpf)
    float tt = (e - 1.f) * __builtin_amdgcn_rcpf(e + 1.f);
#else
    float tt = (e - 1.f) / (e + 1.f);
#endif
    float hx = 0.5f * x;
    return fmaf(hx, tt, hx);
}

#define MFMA16(a, b, c) __builtin_amdgcn_mfma_f32_16x16x32_f16(a, b, c, 0, 0, 0)

// ---- prep: dtype detect + fp16 transposed weights + folded BN + adj32 (R8-proven) ----
__global__ __launch_bounds__(256) void prep(
    const void* adj,
    const void* W0, const void* b0, const void* S0, const void* sb0,
    const void* g0, const void* be0, const void* m0, const void* v0,
    const void* W1, const void* b1, const void* g1, const void* be1, const void* m1, const void* v1,
    const void* W2, const void* b2, const void* g2, const void* be2, const void* m2, const void* v2,
    const void* tW1, const void* tb1, const void* tW2,
    void* ws)
{
    f16* H = (f16*)ws; float* F = (float*)ws;
    const int bi = blockIdx.x, t = threadIdx.x;
    if (bi == 0) {
        const int fW = detect_bf16(W0), fS = detect_bf16(S0);
        for (int i = t; i < NF * 128; i += 256) {
            int k = i >> 7, n = i & 127;
            H[HO_W0 + n * 64 + k] = (f16)ldv(W0, i, fW);
            H[HO_S0 + n * 64 + k] = (f16)ldv(S0, i, fS);
        }
        for (int i = t; i < 128 * 16; i += 256) {
            int n = i >> 4, k = 48 + (i & 15);
            if (k >= NF) { H[HO_W0 + n * 64 + k] = (f16)0.f; H[HO_S0 + n * 64 + k] = (f16)0.f; }
        }
    } else if (bi == 1) {
        const int f = detect_bf16(W1);
        for (int i = t; i < 128 * 128; i += 256) {
            int k = i >> 7, n = i & 127;
            H[HO_W1 + n * 128 + k] = (f16)ldv(W1, i, f);
        }
    } else if (bi == 2) {
        const int f = detect_bf16(W2);
        for (int i = t; i < 128 * 128; i += 256) {
            int k = i >> 7, n = i & 127;
            H[HO_W2 + n * 128 + k] = (f16)ldv(W2, i, f);
        }
    } else if (bi == 3) {
        const int f = detect_bf16(tW1);
        for (int i = t; i < 128 * 128; i += 256) {
            int k = i >> 7, n = i & 127;
            H[HO_TW1 + n * 128 + k] = (f16)ldv(tW1, i, f);
        }
    } else {
        if (t < 128) {
            int c = t;
            {
                float g = ldv(g0,c,detect_bf16(g0)), be = ldv(be0,c,detect_bf16(be0));
                float m = ldv(m0,c,detect_bf16(m0)), v = ldv(v0,c,detect_bf16(v0));
                float b = ldv(b0,c,detect_bf16(b0));
                float A = g * rsqrtf(v + 1e-5f);
                F[FO_A0 + 0*256 + c] = A; F[FO_A0 + 0*256 + 128 + c] = (b - m)*A + be;
            }
            {
                float g = ldv(g1,c,detect_bf16(g1)), be = ldv(be1,c,detect_bf16(be1));
                float m = ldv(m1,c,detect_bf16(m1)), v = ldv(v1,c,detect_bf16(v1));
                float b = ldv(b1,c,detect_bf16(b1));
                float A = g * rsqrtf(v + 1e-5f);
                F[FO_A0 + 1*256 + c] = A; F[FO_A0 + 1*256 + 128 + c] = (b - m)*A + be;
            }
            {
                float g = ldv(g2,c,detect_bf16(g2)), be = ldv(be2,c,detect_bf16(be2));
                float m = ldv(m2,c,detect_bf16(m2)), v = ldv(v2,c,detect_bf16(v2));
                float b = ldv(b2,c,detect_bf16(b2));
                float A = g * rsqrtf(v + 1e-5f);
                F[FO_A0 + 2*256 + c] = A; F[FO_A0 + 2*256 + 128 + c] = (b - m)*A + be;
            }
            F[FO_SB0 + c] = ldv(sb0, c, detect_bf16(sb0));
            F[FO_TB1 + c] = ldv(tb1, c, detect_bf16(tb1));
            F[FO_TW2 + c] = ldv(tW2, c, detect_bf16(tW2));
        }
        const int fA = detect_bf16(adj);
        for (int i = t; i < 1024; i += 256) {
            int r = i >> 5, c = i & 31;
            float v = (r < 25 && c < 25) ? ldv(adj, (long)r*NJ + c, fA) : 0.f;
            H[HO_ADJ32 + i] = (f16)v;
        }
    }
}

// ==== Pt write: P joint-rows 0..24 -> B-layout [f][n][k] (mt 0..3 all dense) ====
#define PTWRITE(ACC)                                                            \
    _Pragma("unroll")                                                           \
    for (int mt = 0; mt < 4; mt++) {                                            \
        const int fF = mt >> 1;                                                 \
        const int jb = (mt & 1) * 16;                                           \
        _Pragma("unroll")                                                       \
        for (int nt = 0; nt < 2; nt++) {                                        \
            f16* pp = Pt + (fF*128 + (nt ? c1 : c0))*PSTR;                      \
            _Pragma("unroll")                                                   \
            for (int r2 = 0; r2 < 4; r2 += 2) {                                 \
                int j0 = jb + q*4 + r2;                                         \
                if (j0 + 1 < 25) {                                              \
                    h2 v2w = { (f16)ACC[mt][nt][r2], (f16)ACC[mt][nt][r2+1] };  \
                    *(h2*)(pp + j0) = v2w;                                      \
                } else if (j0 < 25) {                                           \
                    pp[j0] = (f16)ACC[mt][nt][r2];                              \
                }                                                               \
            }                                                                   \
        }                                                                       \
    }

// ==== adjmix MFMA + register epilogue: hz/h32 updated in place ====
#define ADJEPI(L, WRHB) {                                                       \
    f32x4 zac[2][2][2];                                                         \
    _Pragma("unroll")                                                           \
    for (int fF = 0; fF < 2; fF++) {                                            \
        _Pragma("unroll")                                                       \
        for (int nt = 0; nt < 2; nt++) {                                        \
            half8 bz = *(const half8*)(Pt + (fF*128 + (nt?c1:c0))*PSTR + q*8);  \
            zac[fF][0][nt] = MFMA16(afadj0, bz, z4);                            \
            zac[fF][1][nt] = MFMA16(afadj1, bz, z4);                            \
        }                                                                       \
    }                                                                           \
    _Pragma("unroll")                                                           \
    for (int nt = 0; nt < 2; nt++) {                                            \
        const int cc = nt ? c1 : c0;                                            \
        const float Av = rA[L][nt], Dv = rD[L][nt];                             \
        _Pragma("unroll")                                                       \
        for (int fF = 0; fF < 2; fF++) {                                        \
            _Pragma("unroll")                                                   \
            for (int m2 = 0; m2 < 2; m2++) {                                    \
                _Pragma("unroll")                                               \
                for (int r4 = 0; r4 < 4; r4++) {                                \
                    float zv = (m2 == 0) ? zac[fF][0][nt][r4]                   \
                             : (jlt[r4] ? zac[fF][1][nt][r4]                    \
                                        : acc[2*fF+1][nt][r4]);                 \
                    float hnew = gelu_t(fmaf(zv, Av, Dv)) + hz[fF][m2][nt][r4]; \
                    hz[fF][m2][nt][r4] = hnew;                                  \
                    if (WRHB)                                                   \
                        hb[((2*fF+m2)*16 + q*4 + r4)*HSTR + cc] = (f16)hnew;    \
                }                                                               \
            }                                                                   \
            {                                                                   \
                float hnew = gelu_t(fmaf(acc[4][nt][fF], Av, Dv)) + h32[fF][nt];\
                h32[fF][nt] = (q == 0) ? hnew : 0.f;                            \
                if (WRHB && q == 0)                                             \
                    hb[(64 + fF)*HSTR + cc] = (f16)hnew;                        \
            }                                                                   \
        }                                                                       \
    }                                                                           \
}

// ==== main GEMM over K=128 weights, 5 M-tiles ====
#define GEMM128(WOFF)                                                           \
    {                                                                           \
        half8 bf[2][4];                                                         \
        _Pragma("unroll")                                                       \
        for (int nt = 0; nt < 2; nt++)                                          \
            _Pragma("unroll")                                                   \
            for (int ks = 0; ks < 4; ks++)                                      \
                bf[nt][ks] = *(const half8*)(HW + (WOFF) + (nt?c1:c0)*128 + ks*32 + q*8); \
        _Pragma("unroll")                                                       \
        for (int mt = 0; mt < 5; mt++) { acc[mt][0] = z4; acc[mt][1] = z4; }    \
        _Pragma("unroll")                                                       \
        for (int mt = 0; mt < 5; mt++) {                                        \
            const int m = mt*16 + ml;                                           \
            _Pragma("unroll")                                                   \
            for (int ks = 0; ks < 4; ks++) {                                    \
                half8 af = *(const half8*)(hb + m*HSTR + ks*32 + q*8);          \
                acc[mt][0] = MFMA16(af, bf[0][ks], acc[mt][0]);                 \
                acc[mt][1] = MFMA16(af, bf[1][ks], acc[mt][1]);                 \
            }                                                                   \
        }                                                                       \
    }

__global__ __launch_bounds__(256) void gcn_mfma(const void* __restrict__ x,
                                                void* __restrict__ ws)
{
    const f16* HW = (const f16*)ws;
    float* F = (float*)ws;
    float* xt_g = F + FO_XT;
    float* sc_g = F + FO_SC;

    __shared__ __align__(16) f16 hb[80 * HSTR];       // 21.76 KB
    __shared__ __align__(16) f16 Pt[2 * 128 * PSTR];  // 20.48 KB
    __shared__ float rbuf4[4];
    __shared__ int sfx;
    float* xtb = (float*)Pt;        // alias; used only after ADJEPI(2)+sync

    const int t = threadIdx.x, lane = t & 63, wv = t >> 6;
    const int q = lane >> 4, ml = lane & 15;
    const int n0 = wv * 32;
    const int c0 = n0 + ml, c1 = n0 + 16 + ml;
    const f32x4 z4 = {0.f, 0.f, 0.f, 0.f};
    const bool jlt[4] = { q <= 2, q <= 1, q <= 1, q <= 1 };   // 16+q*4+r4 < 25
    const half8 zero8 = {(f16)0.f,(f16)0.f,(f16)0.f,(f16)0.f,(f16)0.f,(f16)0.f,(f16)0.f,(f16)0.f};

    if (t == 0) sfx = detect_bf16(x);
    // zero Pt k = 24..39 (k>=25 must read 0 in adjmix B-frags; k=24 rewritten per layer)
#pragma unroll
    for (int i = t; i < 512; i += 256) {
        int fF = i >> 8, rem = i & 255, n = rem >> 1, ch = rem & 1;
        *(half8*)(Pt + (fF*128 + n)*PSTR + 24 + ch*8) = zero8;
    }

    // hoisted per-channel BN constants + sb0
    float rA[3][2], rD[3][2];
#pragma unroll
    for (int L = 0; L < 3; L++) {
        rA[L][0] = F[FO_A0 + L*256 + c0];        rA[L][1] = F[FO_A0 + L*256 + c1];
        rD[L][0] = F[FO_A0 + L*256 + 128 + c0];  rD[L][1] = F[FO_A0 + L*256 + 128 + c1];
    }
    const float sb0a = F[FO_SB0 + c0], sb0b = F[FO_SB0 + c1];
    // adjacency A-frags (rows ml and 16+ml), hoisted for all 3 layers
    half8 afadj0 = *(const half8*)(HW + HO_ADJ32 + ml*32 + q*8);
    half8 afadj1 = *(const half8*)(HW + HO_ADJ32 + (16+ml)*32 + q*8);
    __syncthreads();

    // ---- stage x -> hb: frame f j<32 -> row f*32+j; j==32 -> row 64+f ----
    {
        const int fX = sfx;
        const long xb = (long)blockIdx.x * (SPB * NJ * NF);
#pragma unroll 1
        for (int it = 0; it < 3; it++) {
            int g = t + it * 256;
            if (g < 66 * 8) {
                int r = g >> 3, blk = g & 7;
                int fF = (r >= 33) ? 1 : 0;
                int j = r - 33 * fF;
                int fr = (j < 32) ? (fF * 32 + j) : (64 + fF);
                half8 o;
                if (!fX) {
                    const float* base = (const float*)x + xb + (long)r * NF + blk * 8;
                    if (blk < 6) {
                        float4 v0 = *(const float4*)base;
                        float4 v1 = *(const float4*)(base + 4);
                        o[0]=(f16)v0.x; o[1]=(f16)v0.y; o[2]=(f16)v0.z; o[3]=(f16)v0.w;
                        o[4]=(f16)v1.x; o[5]=(f16)v1.y; o[6]=(f16)v1.z; o[7]=(f16)v1.w;
                    } else if (blk == 6) {
                        float4 v0 = *(const float4*)base;
                        o = zero8;
                        o[0]=(f16)v0.x; o[1]=(f16)v0.y; o[2]=(f16)v0.z; o[3]=(f16)v0.w;
                    } else o = zero8;
                } else {
                    long rb = xb + (long)r * NF;
#pragma unroll
                    for (int i = 0; i < 8; i++) {
                        int cx = blk * 8 + i;
                        o[i] = (f16)(cx < NF ? bf2f(((const u16*)x)[rb + cx]) : 0.f);
                    }
                }
                *(half8*)(hb + fr * HSTR + blk * 8) = o;
            }
        }
    }
    __syncthreads();

    f32x4 acc[5][2];
    float hz[2][2][2][4];   // [frame][m2][nt][r4] — h carried in registers
    float h32[2][2];

    // ================= layer 0 (K=64): P = x@W0, skip = x@S0 =================
    {
        half8 bw[2][2], bs[2][2];
#pragma unroll
        for (int nt = 0; nt < 2; nt++) {
            int n = nt ? c1 : c0;
#pragma unroll
            for (int ks = 0; ks < 2; ks++) {
                bw[nt][ks] = *(const half8*)(HW + HO_W0 + n*64 + ks*32 + q*8);
                bs[nt][ks] = *(const half8*)(HW + HO_S0 + n*64 + ks*32 + q*8);
            }
        }
        f32x4 acs[5][2];
#pragma unroll
        for (int mt = 0; mt < 5; mt++) { acc[mt][0]=z4; acc[mt][1]=z4; acs[mt][0]=z4; acs[mt][1]=z4; }
#pragma unroll
        for (int mt = 0; mt < 5; mt++) {
            const int m = mt*16 + ml;
            half8 a0 = *(const half8*)(hb + m*HSTR + q*8);
            half8 a1 = *(const half8*)(hb + m*HSTR + 32 + q*8);
            acc[mt][0] = MFMA16(a0, bw[0][0], acc[mt][0]);
            acc[mt][0] = MFMA16(a1, bw[0][1], acc[mt][0]);
            acc[mt][1] = MFMA16(a0, bw[1][0], acc[mt][1]);
            acc[mt][1] = MFMA16(a1, bw[1][1], acc[mt][1]);
            acs[mt][0] = MFMA16(a0, bs[0][0], acs[mt][0]);
            acs[mt][0] = MFMA16(a1, bs[0][1], acs[mt][0]);
            acs[mt][1] = MFMA16(a0, bs[1][0], acs[mt][1]);
            acs[mt][1] = MFMA16(a1, bs[1][1], acs[mt][1]);
        }
        __syncthreads();               // all x A-reads done before hb/Pt writes
        PTWRITE(acc)
        // seed hz/h32 with skip + sb0
#pragma unroll
        for (int fF = 0; fF < 2; fF++)
#pragma unroll
            for (int m2 = 0; m2 < 2; m2++)
#pragma unroll
                for (int nt = 0; nt < 2; nt++)
#pragma unroll
                    for (int r4 = 0; r4 < 4; r4++)
                        hz[fF][m2][nt][r4] = acs[2*fF+m2][nt][r4] + (nt ? sb0b : sb0a);
#pragma unroll
        for (int fF = 0; fF < 2; fF++)
#pragma unroll
            for (int nt = 0; nt < 2; nt++)
                h32[fF][nt] = (q == 0) ? (acs[4][nt][fF] + (nt ? sb0b : sb0a)) : 0.f;
        ADJEPI(0, 1)
        __syncthreads();
    }

    // ================= layer 1 =================
    GEMM128(HO_W1)
    __syncthreads();
    PTWRITE(acc)
    ADJEPI(1, 1)
    __syncthreads();

    // ================= layer 2 (no hb writes needed) =================
    GEMM128(HO_W2)
    __syncthreads();
    PTWRITE(acc)
    ADJEPI(2, 0)
    __syncthreads();                   // Pt reads done before xtb alias writes

    // ================= mean over joints (from regs) + score MLP =================
#pragma unroll
    for (int fF = 0; fF < 2; fF++)
#pragma unroll
        for (int nt = 0; nt < 2; nt++) {
            float s = h32[fF][nt];
#pragma unroll
            for (int m2 = 0; m2 < 2; m2++)
#pragma unroll
                for (int r4 = 0; r4 < 4; r4++) s += hz[fF][m2][nt][r4];
            s += __shfl_xor(s, 16, 64);
            s += __shfl_xor(s, 32, 64);
            float xtc = s * (1.0f / 33.0f);
            if (q == 0) {
                int cc = nt ? c1 : c0;
                xtb[fF * 128 + cc] = xtc;
                xt_g[((long)blockIdx.x * SPB + fF) * NH + cc] = xtc;
            }
        }
    __syncthreads();

    {
        const int fF = t >> 7, c = t & 127;
        float u = 0.f;
#pragma unroll
        for (int kk = 0; kk < 16; kk++) {
            half8 wv8 = *(const half8*)(HW + HO_TW1 + c*128 + kk*8);
#pragma unroll
            for (int i = 0; i < 8; i++)
                u = fmaf(xtb[fF*128 + kk*8 + i], (float)wv8[i], u);
        }
        float r = gelu_t(u + F[FO_TB1 + c]) * F[FO_TW2 + c];  // tb2 omitted (shift-inv)
#pragma unroll
        for (int off = 32; off > 0; off >>= 1) r += __shfl_xor(r, off, 64);
        if (lane == 0) rbuf4[wv] = r;
        __syncthreads();
        if (t == 0) {
            sc_g[blockIdx.x * SPB + 0] = rbuf4[0] + rbuf4[1];
            sc_g[blockIdx.x * SPB + 1] = rbuf4[2] + rbuf4[3];
        }
    }
}

// ---- softmax over T + weighted sum -> out[B,H]; shuffle reductions (R8-proven) ----
__global__ __launch_bounds__(256) void attn_pool(
    const void* __restrict__ x,
    const float* __restrict__ xt_ws, const float* __restrict__ score_ws,
    void* __restrict__ out)
{
    __shared__ float ew[NT];
    __shared__ float red[8];
    __shared__ float pb[256];
    __shared__ int sfx2;
    const int t = threadIdx.x, lane = t & 63, wv = t >> 6;
    const int b = blockIdx.x >> 2, qr = blockIdx.x & 3;

    if (t == 0) sfx2 = detect_bf16(x);
    float sv = score_ws[b * NT + t];
    float m = sv;
#pragma unroll
    for (int off = 32; off > 0; off >>= 1) m = fmaxf(m, __shfl_xor(m, off, 64));
    if (lane == 0) red[wv] = m;
    __syncthreads();
    float mx = fmaxf(fmaxf(red[0], red[1]), fmaxf(red[2], red[3]));
    float e = __expf(sv - mx);
    ew[t] = e;
    float d = e;
#pragma unroll
    for (int off = 32; off > 0; off >>= 1) d += __shfl_xor(d, off, 64);
    if (lane == 0) red[4 + wv] = d;
    __syncthreads();
    float den = red[4] + red[5] + red[6] + red[7];

    const int cl = t & 31, ch = t >> 5;
    const int c = qr * 32 + cl;
    float a = 0.f;
#pragma unroll 4
    for (int i = ch * 32; i < ch * 32 + 32; i++)
        a = fmaf(ew[i], xt_ws[((long)b * NT + i) * NH + c], a);
    pb[t] = a;
    __syncthreads();
    if (t < 128) pb[t] += pb[t + 128];
    __syncthreads();
    if (t < 64) pb[t] += pb[t + 64];
    __syncthreads();
    if (t < 32) {
        float r = (pb[t] + pb[t + 32]) / den;
        if (sfx2) ((__hip_bfloat16*)out)[b * NH + qr * 32 + t] = __float2bfloat16(r);
        else      ((float*)out)[b * NH + qr * 32 + t] = r;
    }
}

extern "C" void kernel_launch(void* const* d_in, const int* in_sizes, int n_in,
                              void* d_out, int out_size, void* d_ws, size_t ws_size,
                              hipStream_t stream) {
    prep<<<5, 256, 0, stream>>>(
        d_in[1],
        d_in[2], d_in[3], d_in[4], d_in[5],
        d_in[6], d_in[7], d_in[8], d_in[9],
        d_in[10], d_in[11], d_in[12], d_in[13], d_in[14], d_in[15],
        d_in[16], d_in[17], d_in[18], d_in[19], d_in[20], d_in[21],
        d_in[22], d_in[23], d_in[24],
        d_ws);
    gcn_mfma<<<NBLKS, 256, 0, stream>>>(d_in[0], d_ws);
    float* F = (float*)d_ws;
    attn_pool<<<NB * 4, 256, 0, stream>>>(d_in[0], F + FO_XT, F + FO_SC, d_out);
}